// Round 13
// baseline (209.252 us; speedup 1.0000x reference)
//
#include <hip/hip_runtime.h>
#include <hip/hip_fp16.h>

#define NN 50000
#define NE 800000

typedef unsigned short u16;
typedef float v2f __attribute__((ext_vector_type(2)));

// ---- 16-lane all-reduce on the VALU pipe via DPP (no DS ops) ----
template <int CTRL>
__device__ __forceinline__ float dpp_add(float p) {
  const int v = __builtin_amdgcn_update_dpp(0, __float_as_int(p), CTRL, 0xF, 0xF, true);
  return p + __int_as_float(v);
}
__device__ __forceinline__ float red16(float p) {
  p = dpp_add<0xB1>(p);   // quad_perm [1,0,3,2]
  p = dpp_add<0x4E>(p);   // quad_perm [2,3,0,1]
  p = dpp_add<0x141>(p);  // row_half_mirror
  p = dpp_add<0x140>(p);  // row_mirror
  return p;
}

// ---------------- K1: fused QKV + skip GEMM, 128-node tile, 8x4 micro ------
// + (y==1) dst histogram slice
// q stored natural [n][128] fp32.
// kv stored [n][64] x u32 fp8-e4m3: entry e: k at 2e, v at 2e+1.
__global__ __launch_bounds__(256) void k_gemm_qkv(
    const float* __restrict__ x,
    const float* __restrict__ Wq, const float* __restrict__ bq,
    const float* __restrict__ Wk, const float* __restrict__ bk,
    const float* __restrict__ Wv, const float* __restrict__ bv,
    const float* __restrict__ Wskip, const float* __restrict__ bskip,
    const int* __restrict__ ei, int* __restrict__ cnt,
    float* __restrict__ qs, unsigned* __restrict__ kvp, float* __restrict__ skip)
{
  const int t = threadIdx.x;

  if (blockIdx.y == 1) {  // histogram slice: 391 blocks x 2048 edges
    const int e0 = blockIdx.x * 2048 + t;
    #pragma unroll
    for (int it = 0; it < 8; it++) {
      const int e = e0 + it * 256;
      if (e < NE) atomicAdd(&cnt[ei[NE + e]], 1);
    }
    return;
  }

  __shared__ float xsT[64][132];   // [ch][row], 128 rows padded to 132
  __shared__ float wsT[64][68];    // [ch][outcol]
  const int tileN = blockIdx.x * 128;

  {  // load x tile once: thread -> row nl = t>>1, half c0 = (t&1)*32
    const int nl = t >> 1, c0 = (t & 1) * 32;
    const int n = tileN + nl;
    #pragma unroll
    for (int j = 0; j < 8; j++) {
      float4 a = (n < NN) ? *(const float4*)(x + (size_t)n * 64 + c0 + j * 4)
                          : make_float4(0.f, 0.f, 0.f, 0.f);
      xsT[c0 + j * 4 + 0][nl] = a.x;
      xsT[c0 + j * 4 + 1][nl] = a.y;
      xsT[c0 + j * 4 + 2][nl] = a.z;
      xsT[c0 + j * 4 + 3][nl] = a.w;
    }
  }

  const int tx2 = t & 15;   // output-col group (4 cols)
  const int ty2 = t >> 4;   // row group (8 rows)

  for (int jt = 0; jt < 7; jt++) {
    const float* W; const float* bias; int rowbase;
    if (jt < 2)      { W = Wq;    bias = bq;    rowbase = jt * 64; }
    else if (jt < 4) { W = Wk;    bias = bk;    rowbase = (jt - 2) * 64; }
    else if (jt < 6) { W = Wv;    bias = bv;    rowbase = (jt - 4) * 64; }
    else             { W = Wskip; bias = bskip; rowbase = 0; }

    __syncthreads();  // previous MAC done (and xsT ready on first iter)
    {
      const int jl = t >> 2, c0 = (t & 3) * 16;
      const float4* wr = (const float4*)(W + (size_t)(rowbase + jl) * 64 + c0);
      float4 b0 = wr[0], b1 = wr[1], b2 = wr[2], b3 = wr[3];
      wsT[c0 +  0][jl] = b0.x; wsT[c0 +  1][jl] = b0.y; wsT[c0 +  2][jl] = b0.z; wsT[c0 +  3][jl] = b0.w;
      wsT[c0 +  4][jl] = b1.x; wsT[c0 +  5][jl] = b1.y; wsT[c0 +  6][jl] = b1.z; wsT[c0 +  7][jl] = b1.w;
      wsT[c0 +  8][jl] = b2.x; wsT[c0 +  9][jl] = b2.y; wsT[c0 + 10][jl] = b2.z; wsT[c0 + 11][jl] = b2.w;
      wsT[c0 + 12][jl] = b3.x; wsT[c0 + 13][jl] = b3.y; wsT[c0 + 14][jl] = b3.z; wsT[c0 + 15][jl] = b3.w;
    }
    __syncthreads();

    float acc[8][4];
    #pragma unroll
    for (int i = 0; i < 8; i++)
      #pragma unroll
      for (int j = 0; j < 4; j++) acc[i][j] = 0.f;

    #pragma unroll 8
    for (int kk = 0; kk < 64; kk++) {
      const float4 a0 = *(const float4*)&xsT[kk][ty2 * 8];
      const float4 a1 = *(const float4*)&xsT[kk][ty2 * 8 + 4];
      const float4 b  = *(const float4*)&wsT[kk][tx2 * 4];
      acc[0][0] += a0.x * b.x; acc[0][1] += a0.x * b.y; acc[0][2] += a0.x * b.z; acc[0][3] += a0.x * b.w;
      acc[1][0] += a0.y * b.x; acc[1][1] += a0.y * b.y; acc[1][2] += a0.y * b.z; acc[1][3] += a0.y * b.w;
      acc[2][0] += a0.z * b.x; acc[2][1] += a0.z * b.y; acc[2][2] += a0.z * b.z; acc[2][3] += a0.z * b.w;
      acc[3][0] += a0.w * b.x; acc[3][1] += a0.w * b.y; acc[3][2] += a0.w * b.z; acc[3][3] += a0.w * b.w;
      acc[4][0] += a1.x * b.x; acc[4][1] += a1.x * b.y; acc[4][2] += a1.x * b.z; acc[4][3] += a1.x * b.w;
      acc[5][0] += a1.y * b.x; acc[5][1] += a1.y * b.y; acc[5][2] += a1.y * b.z; acc[5][3] += a1.y * b.w;
      acc[6][0] += a1.z * b.x; acc[6][1] += a1.z * b.y; acc[6][2] += a1.z * b.z; acc[6][3] += a1.z * b.w;
      acc[7][0] += a1.w * b.x; acc[7][1] += a1.w * b.y; acc[7][2] += a1.w * b.z; acc[7][3] += a1.w * b.w;
    }

    const int col0 = rowbase + tx2 * 4;
    const float4 bb = *(const float4*)(bias + col0);
    #pragma unroll
    for (int i = 0; i < 8; i++) {
      const int n = tileN + ty2 * 8 + i;
      if (n >= NN) continue;
      const float r0 = acc[i][0] + bb.x, r1 = acc[i][1] + bb.y;
      const float r2 = acc[i][2] + bb.z, r3 = acc[i][3] + bb.w;
      if (jt < 2) {
        *(float4*)(qs + (size_t)n * 128 + col0) = make_float4(r0, r1, r2, r3);
      } else if (jt < 6) {
        const int entry = col0 >> 2;
        unsigned pk = 0;
        pk = __builtin_amdgcn_cvt_pk_fp8_f32(r0, r1, pk, false);
        pk = __builtin_amdgcn_cvt_pk_fp8_f32(r2, r3, pk, true);
        kvp[(size_t)n * 64 + entry * 2 + ((jt >= 4) ? 1 : 0)] = pk;
      } else {
        *(float4*)(skip + (size_t)n * 64 + col0) = make_float4(r0, r1, r2, r3);
      }
    }
  }
}

// ---------------- S2: single merged scan (49 blocks; self-computed prefix) --
// reads cnt (read-only), writes rowptr[] and cntW[i] = rowptr[i+1]
__global__ __launch_bounds__(1024) void k_scan(
    const int* __restrict__ cnt, int* __restrict__ rowptr, int* __restrict__ cntW) {
  __shared__ int wsum[16];
  __shared__ int boff_s;
  const int t = threadIdx.x, lane = t & 63, wid = t >> 6;
  const int b = blockIdx.x;

  // prefix: sum of cnt[0 .. b*1024)
  {
    int pre = 0;
    for (int j = t; j < b * 1024; j += 1024) pre += cnt[j];
    #pragma unroll
    for (int m = 1; m <= 32; m <<= 1) pre += __shfl_xor(pre, m);
    if (lane == 0) wsum[wid] = pre;
    __syncthreads();
    if (t == 0) {
      int s = 0;
      #pragma unroll
      for (int j = 0; j < 16; j++) s += wsum[j];
      boff_s = s;
    }
    __syncthreads();
  }

  const int i = b * 1024 + t;
  const int val = (i < NN) ? cnt[i] : 0;
  int incl = val;
  #pragma unroll
  for (int off = 1; off < 64; off <<= 1) {
    int n = __shfl_up(incl, off, 64);
    if (lane >= off) incl += n;
  }
  if (lane == 63) wsum[wid] = incl;
  __syncthreads();
  if (t < 16) {
    int wv = wsum[t];
    int wincl = wv;
    #pragma unroll
    for (int off = 1; off < 16; off <<= 1) {
      int n = __shfl_up(wincl, off, 64);
      if (t >= off) wincl += n;
    }
    wsum[t] = wincl - wv;
  }
  __syncthreads();
  if (i < NN) {
    const int inc_g = boff_s + wsum[wid] + incl;   // inclusive global
    rowptr[i] = inc_g - val;                        // exclusive
    cntW[i]   = inc_g;                              // = rowptr[i+1], for fill
  }
  if (b == 0 && t == 0) rowptr[NN] = NE;
}

// ---------------- S3: bucket-fill, 4B records {src:16 | ea_fp16:16} ---------
__global__ __launch_bounds__(256) void k_fill(
    const int* __restrict__ ei, const float* __restrict__ ea,
    int* __restrict__ cntW, unsigned* __restrict__ epk) {
  const int e = blockIdx.x * 256 + threadIdx.x;
  if (e < NE) {
    const int dst = ei[NE + e];
    const int idx = atomicSub(&cntW[dst], 1) - 1;
    const unsigned rec = (unsigned)ei[e] |
        ((unsigned)__half_as_ushort(__float2half_rn(ea[e])) << 16);
    epk[idx] = rec;
  }
}

// ------- K2: per-dst softmax + agg (fp8 kv, DPP reduce, 8-edge unroll),
//         single barrier after wlT staging; waves independent afterwards -----
__global__ __launch_bounds__(256) void k_fused(
    const float* __restrict__ qs, const unsigned* __restrict__ kvp,
    const float* __restrict__ skip, const float* __restrict__ x,
    const int* __restrict__ rowptr, const unsigned* __restrict__ epk,
    const float* __restrict__ We,
    const float* __restrict__ Wl, const float* __restrict__ bl,
    const float* __restrict__ g0, const float* __restrict__ b0,
    const float* __restrict__ g1, const float* __restrict__ b1,
    float* __restrict__ out)
{
  __shared__ float wlT[64][65];   // wlT[k][j] = Wl[j][k]
  __shared__ float scx[4][64];    // per-wave scratch (transpose + x1 broadcast)
  const int t = threadIdx.x;
  {
    const int jl = t >> 2, c0 = (t & 3) * 16;
    const float4* wr = (const float4*)(Wl + (size_t)jl * 64 + c0);
    float4 w0 = wr[0], w1 = wr[1], w2 = wr[2], w3 = wr[3];
    wlT[c0 +  0][jl] = w0.x; wlT[c0 +  1][jl] = w0.y; wlT[c0 +  2][jl] = w0.z; wlT[c0 +  3][jl] = w0.w;
    wlT[c0 +  4][jl] = w1.x; wlT[c0 +  5][jl] = w1.y; wlT[c0 +  6][jl] = w1.z; wlT[c0 +  7][jl] = w1.w;
    wlT[c0 +  8][jl] = w2.x; wlT[c0 +  9][jl] = w2.y; wlT[c0 + 10][jl] = w2.z; wlT[c0 + 11][jl] = w2.w;
    wlT[c0 + 12][jl] = w3.x; wlT[c0 + 13][jl] = w3.y; wlT[c0 + 14][jl] = w3.z; wlT[c0 + 15][jl] = w3.w;
  }
  __syncthreads();  // the ONLY barrier

  const int w = t >> 6;
  const int dst = __builtin_amdgcn_readfirstlane(blockIdx.x * 4 + w);
  const int lane = t & 63;
  const int half = lane >> 5;
  const int el = lane & 31;

  const float4 qv = ((const float4*)(qs + (size_t)dst * 128))[el];
  const float4 we4 = ((const float4*)We)[el];
  const float skipv = skip[(size_t)dst * 64 + lane];
  const float xv    = x[(size_t)dst * 64 + lane];

  const float qwe = red16(qv.x * we4.x + qv.y * we4.y + qv.z * we4.z + qv.w * we4.w);

  const int base = rowptr[dst];
  const int deg  = rowptr[dst + 1] - base;
  const uint2* kv8 = (const uint2*)kvp;
  const unsigned* ep = epk + base;

  float s = 0.f, sw = 0.f;
  float sv0 = 0.f, sv1 = 0.f, sv2 = 0.f, sv3 = 0.f;

  const float SCL = 0.18033688011112042f;  // 0.125*log2(e)

#define UNPACK_W(er) __half2float(__ushort_as_half((unsigned short)((er) >> 16)))
#define PROC(u, wg, mask)                                                   \
  {                                                                         \
    const v2f k01 = __builtin_amdgcn_cvt_pk_f32_fp8((u).x, false);          \
    const v2f k23 = __builtin_amdgcn_cvt_pk_f32_fp8((u).x, true);           \
    const v2f v01 = __builtin_amdgcn_cvt_pk_f32_fp8((u).y, false);          \
    const v2f v23 = __builtin_amdgcn_cvt_pk_f32_fp8((u).y, true);           \
    const float p = red16(qv.x * k01.x + qv.y * k01.y +                     \
                          qv.z * k23.x + qv.w * k23.y);                     \
    float e_ = exp2f((p + (wg) * qwe) * SCL);                               \
    e_ = (mask) ? e_ : 0.f;                                                 \
    s += e_; sw += e_ * (wg);                                               \
    sv0 += e_ * v01.x; sv1 += e_ * v01.y;                                   \
    sv2 += e_ * v23.x; sv3 += e_ * v23.y;                                   \
  }

  int i = 0;
  for (; i + 8 <= deg; i += 8) {
    const unsigned er0 = ep[i + half];
    const unsigned er1 = ep[i + 2 + half];
    const unsigned er2 = ep[i + 4 + half];
    const unsigned er3 = ep[i + 6 + half];
    const uint2 u0 = kv8[(size_t)(er0 & 0xFFFFu) * 32 + el];
    const uint2 u1 = kv8[(size_t)(er1 & 0xFFFFu) * 32 + el];
    const uint2 u2 = kv8[(size_t)(er2 & 0xFFFFu) * 32 + el];
    const uint2 u3 = kv8[(size_t)(er3 & 0xFFFFu) * 32 + el];
    PROC(u0, UNPACK_W(er0), true)
    PROC(u1, UNPACK_W(er1), true)
    PROC(u2, UNPACK_W(er2), true)
    PROC(u3, UNPACK_W(er3), true)
  }
  for (; i + 4 <= deg; i += 4) {
    const unsigned er0 = ep[i + half];
    const unsigned er1 = ep[i + 2 + half];
    const uint2 u0 = kv8[(size_t)(er0 & 0xFFFFu) * 32 + el];
    const uint2 u1 = kv8[(size_t)(er1 & 0xFFFFu) * 32 + el];
    PROC(u0, UNPACK_W(er0), true)
    PROC(u1, UNPACK_W(er1), true)
  }
  for (; i < deg; i += 2) {
    const int idx = i + half;
    const bool valid = idx < deg;
    const unsigned er = ep[valid ? idx : (deg - 1)];
    const uint2 u = kv8[(size_t)(er & 0xFFFFu) * 32 + el];
    PROC(u, UNPACK_W(er), valid)
  }
#undef PROC
#undef UNPACK_W

  s  += __shfl_xor(s, 32);
  sw += __shfl_xor(sw, 32);
  sv0 += __shfl_xor(sv0, 32); sv1 += __shfl_xor(sv1, 32);
  sv2 += __shfl_xor(sv2, 32); sv3 += __shfl_xor(sv3, 32);

  float a0 = 0.f, a1 = 0.f, a2 = 0.f, a3 = 0.f;
  if (deg > 0) {
    const float inv = 1.f / s;
    a0 = (sv0 + sw * we4.x) * inv;
    a1 = (sv1 + sw * we4.y) * inv;
    a2 = (sv2 + sw * we4.z) * inv;
    a3 = (sv3 + sw * we4.w) * inv;
  }
  a0 = 0.5f * (a0 + __shfl_xor(a0, 16));
  a1 = 0.5f * (a1 + __shfl_xor(a1, 16));
  a2 = 0.5f * (a2 + __shfl_xor(a2, 16));
  a3 = 0.5f * (a3 + __shfl_xor(a3, 16));
  if (half == 0 && el < 16) {
    ((float4*)scx[w])[el] = make_float4(a0, a1, a2, a3);
  }
  const float hv = scx[w][lane] + skipv;

  // LN0 via dual moments
  float m1 = hv, m2 = hv * hv;
  m1 = red16(m1); m2 = red16(m2);
  m1 += __shfl_xor(m1, 16); m2 += __shfl_xor(m2, 16);
  m1 += __shfl_xor(m1, 32); m2 += __shfl_xor(m2, 32);
  const float mean = m1 * (1.f / 64.f);
  const float var = fmaxf(m2 * (1.f / 64.f) - mean * mean, 0.f);
  const float x1 = xv + (hv - mean) * rsqrtf(var + 1e-5f) * g0[lane] + b0[lane];

  // y = x1 @ Wl^T + bl via per-wave LDS broadcast
  scx[w][lane] = x1;
  float y0 = 0.f, y1 = 0.f, y2 = 0.f, y3 = 0.f;
  #pragma unroll
  for (int kk = 0; kk < 64; kk += 4) {
    const float4 xb = *(const float4*)&scx[w][kk];
    y0 += xb.x * wlT[kk][lane];
    y1 += xb.y * wlT[kk + 1][lane];
    y2 += xb.z * wlT[kk + 2][lane];
    y3 += xb.w * wlT[kk + 3][lane];
  }
  const float y = bl[lane] + (y0 + y1) + (y2 + y3);

  // LN1 via dual moments
  float n1 = y, n2 = y * y;
  n1 = red16(n1); n2 = red16(n2);
  n1 += __shfl_xor(n1, 16); n2 += __shfl_xor(n2, 16);
  n1 += __shfl_xor(n1, 32); n2 += __shfl_xor(n2, 32);
  const float mean2 = n1 * (1.f / 64.f);
  const float var2 = fmaxf(n2 * (1.f / 64.f) - mean2 * mean2, 0.f);
  out[(size_t)dst * 64 + lane] = x1 + (y - mean2) * rsqrtf(var2 + 1e-5f) * g1[lane] + b1[lane];
}

extern "C" void kernel_launch(void* const* d_in, const int* in_sizes, int n_in,
                              void* d_out, int out_size, void* d_ws, size_t ws_size,
                              hipStream_t stream) {
  const float* x     = (const float*)d_in[0];
  const int*   ei    = (const int*)d_in[1];
  const float* ea    = (const float*)d_in[2];
  const float* Wq    = (const float*)d_in[3];
  const float* bq    = (const float*)d_in[4];
  const float* Wk    = (const float*)d_in[5];
  const float* bk    = (const float*)d_in[6];
  const float* Wv    = (const float*)d_in[7];
  const float* bv    = (const float*)d_in[8];
  const float* We    = (const float*)d_in[9];
  const float* Wskip = (const float*)d_in[10];
  const float* bskip = (const float*)d_in[11];
  const float* Wl    = (const float*)d_in[12];
  const float* bl    = (const float*)d_in[13];
  const float* g0    = (const float*)d_in[14];
  const float* b0    = (const float*)d_in[15];
  const float* g1    = (const float*)d_in[16];
  const float* b1    = (const float*)d_in[17];
  float* out = (float*)d_out;

  float* ws = (float*)d_ws;
  size_t off = 0;
  float* qs   = ws + off; off += (size_t)NN * 128;
  unsigned* kvp = (unsigned*)(ws + off); off += (size_t)NN * 64;  // 256B/node fp8
  float* skip = ws + off; off += (size_t)NN * 64;
  int* cnt    = (int*)(ws + off); off += NN;
  int* cntW   = (int*)(ws + off); off += NN;
  int* rowptr = (int*)(ws + off); off += NN + 1;
  unsigned* epk = (unsigned*)(ws + off); off += NE;

  (void)hipMemsetAsync(cnt, 0, (size_t)NN * sizeof(int), stream);

  dim3 gGemm((NN + 127) / 128, 2);  // y==1 -> histogram slice
  hipLaunchKernelGGL(k_gemm_qkv, gGemm, dim3(256), 0, stream,
                     x, Wq, bq, Wk, bk, Wv, bv, Wskip, bskip, ei, cnt, qs, kvp, skip);
  hipLaunchKernelGGL(k_scan, dim3(49), dim3(1024), 0, stream, cnt, rowptr, cntW);
  hipLaunchKernelGGL(k_fill, dim3((NE + 255) / 256), dim3(256), 0, stream,
                     ei, ea, cntW, epk);
  hipLaunchKernelGGL(k_fused, dim3(NN / 4), dim3(256), 0, stream,
                     qs, kvp, skip, x, rowptr, epk, We,
                     Wl, bl, g0, b0, g1, b1, out);
}

// Round 14
// 184.211 us; speedup vs baseline: 1.1359x; 1.1359x over previous
//
#include <hip/hip_runtime.h>
#include <hip/hip_fp16.h>

#define NN 50000
#define NE 800000

typedef unsigned short u16;
typedef float v2f __attribute__((ext_vector_type(2)));

// ---- 16-lane all-reduce on the VALU pipe via DPP (no DS ops) ----
template <int CTRL>
__device__ __forceinline__ float dpp_add(float p) {
  const int v = __builtin_amdgcn_update_dpp(0, __float_as_int(p), CTRL, 0xF, 0xF, true);
  return p + __int_as_float(v);
}
__device__ __forceinline__ float red16(float p) {
  p = dpp_add<0xB1>(p);   // quad_perm [1,0,3,2]
  p = dpp_add<0x4E>(p);   // quad_perm [2,3,0,1]
  p = dpp_add<0x141>(p);  // row_half_mirror
  p = dpp_add<0x140>(p);  // row_mirror
  return p;
}

// ---------------- K1: fused QKV + skip GEMM (64-tile, jt-loop) + histogram --
// q stored natural [n][128] fp32.
// kv stored [n][64] x u32 fp8-e4m3: entry e: k at 2e, v at 2e+1.
__global__ __launch_bounds__(256) void k_gemm_qkv(
    const float* __restrict__ x,
    const float* __restrict__ Wq, const float* __restrict__ bq,
    const float* __restrict__ Wk, const float* __restrict__ bk,
    const float* __restrict__ Wv, const float* __restrict__ bv,
    const float* __restrict__ Wskip, const float* __restrict__ bskip,
    const int* __restrict__ ei, int* __restrict__ cnt,
    float* __restrict__ qs, unsigned* __restrict__ kvp, float* __restrict__ skip)
{
  const int t = threadIdx.x;

  if (blockIdx.y == 1) {  // histogram slice
    const int e0 = blockIdx.x * 1024 + t;
    #pragma unroll
    for (int it = 0; it < 4; it++) {
      const int e = e0 + it * 256;
      if (e < NE) atomicAdd(&cnt[ei[NE + e]], 1);
    }
    return;
  }

  __shared__ float xsT[64][68];
  __shared__ float wsT[64][68];
  const int tileN = blockIdx.x * 64;

  {  // load x tile once
    const int nl = t >> 2, c0 = (t & 3) * 16;
    const int n = tileN + nl;
    float4 a0, a1, a2, a3;
    if (n < NN) {
      const float4* xr = (const float4*)(x + (size_t)n * 64 + c0);
      a0 = xr[0]; a1 = xr[1]; a2 = xr[2]; a3 = xr[3];
    } else {
      a0 = a1 = a2 = a3 = make_float4(0.f, 0.f, 0.f, 0.f);
    }
    xsT[c0 +  0][nl] = a0.x; xsT[c0 +  1][nl] = a0.y; xsT[c0 +  2][nl] = a0.z; xsT[c0 +  3][nl] = a0.w;
    xsT[c0 +  4][nl] = a1.x; xsT[c0 +  5][nl] = a1.y; xsT[c0 +  6][nl] = a1.z; xsT[c0 +  7][nl] = a1.w;
    xsT[c0 +  8][nl] = a2.x; xsT[c0 +  9][nl] = a2.y; xsT[c0 + 10][nl] = a2.z; xsT[c0 + 11][nl] = a2.w;
    xsT[c0 + 12][nl] = a3.x; xsT[c0 + 13][nl] = a3.y; xsT[c0 + 14][nl] = a3.z; xsT[c0 + 15][nl] = a3.w;
  }

  const int tx = t & 15, ty = t >> 4;

  for (int jt = 0; jt < 7; jt++) {
    const float* W; const float* bias; int rowbase;
    if (jt < 2)      { W = Wq;    bias = bq;    rowbase = jt * 64; }
    else if (jt < 4) { W = Wk;    bias = bk;    rowbase = (jt - 2) * 64; }
    else if (jt < 6) { W = Wv;    bias = bv;    rowbase = (jt - 4) * 64; }
    else             { W = Wskip; bias = bskip; rowbase = 0; }

    __syncthreads();
    {
      const int nl = t >> 2, c0 = (t & 3) * 16;
      const float4* wr = (const float4*)(W + (size_t)(rowbase + nl) * 64 + c0);
      float4 b0 = wr[0], b1 = wr[1], b2 = wr[2], b3 = wr[3];
      wsT[c0 +  0][nl] = b0.x; wsT[c0 +  1][nl] = b0.y; wsT[c0 +  2][nl] = b0.z; wsT[c0 +  3][nl] = b0.w;
      wsT[c0 +  4][nl] = b1.x; wsT[c0 +  5][nl] = b1.y; wsT[c0 +  6][nl] = b1.z; wsT[c0 +  7][nl] = b1.w;
      wsT[c0 +  8][nl] = b2.x; wsT[c0 +  9][nl] = b2.y; wsT[c0 + 10][nl] = b2.z; wsT[c0 + 11][nl] = b2.w;
      wsT[c0 + 12][nl] = b3.x; wsT[c0 + 13][nl] = b3.y; wsT[c0 + 14][nl] = b3.z; wsT[c0 + 15][nl] = b3.w;
    }
    __syncthreads();

    float acc[4][4];
    #pragma unroll
    for (int i = 0; i < 4; i++)
      #pragma unroll
      for (int j = 0; j < 4; j++) acc[i][j] = 0.f;

    #pragma unroll 8
    for (int kk = 0; kk < 64; kk++) {
      float4 a = *(const float4*)&xsT[kk][tx * 4];
      float4 b = *(const float4*)&wsT[kk][ty * 4];
      acc[0][0] += a.x * b.x; acc[0][1] += a.x * b.y; acc[0][2] += a.x * b.z; acc[0][3] += a.x * b.w;
      acc[1][0] += a.y * b.x; acc[1][1] += a.y * b.y; acc[1][2] += a.y * b.z; acc[1][3] += a.y * b.w;
      acc[2][0] += a.z * b.x; acc[2][1] += a.z * b.y; acc[2][2] += a.z * b.z; acc[2][3] += a.z * b.w;
      acc[3][0] += a.w * b.x; acc[3][1] += a.w * b.y; acc[3][2] += a.w * b.z; acc[3][3] += a.w * b.w;
    }

    const int n0 = tileN + tx * 4;
    const int col0 = rowbase + ty * 4;
    const float4 bb = *(const float4*)(bias + col0);
    #pragma unroll
    for (int i = 0; i < 4; i++) {
      const int n = n0 + i;
      if (n >= NN) continue;
      const float r0 = acc[i][0] + bb.x, r1 = acc[i][1] + bb.y;
      const float r2 = acc[i][2] + bb.z, r3 = acc[i][3] + bb.w;
      if (jt < 2) {
        *(float4*)(qs + (size_t)n * 128 + col0) = make_float4(r0, r1, r2, r3);
      } else if (jt < 6) {
        const int entry = col0 >> 2;
        unsigned pk = 0;
        pk = __builtin_amdgcn_cvt_pk_fp8_f32(r0, r1, pk, false);
        pk = __builtin_amdgcn_cvt_pk_fp8_f32(r2, r3, pk, true);
        kvp[(size_t)n * 64 + entry * 2 + ((jt >= 4) ? 1 : 0)] = pk;
      } else {
        *(float4*)(skip + (size_t)n * 64 + col0) = make_float4(r0, r1, r2, r3);
      }
    }
  }
}

// ---------------- S2: single merged scan (49 blocks; self-computed prefix) --
// reads cnt (read-only), writes rowptr[] and cntW[i] = rowptr[i+1]
__global__ __launch_bounds__(1024) void k_scan(
    const int* __restrict__ cnt, int* __restrict__ rowptr, int* __restrict__ cntW) {
  __shared__ int wsum[16];
  __shared__ int boff_s;
  const int t = threadIdx.x, lane = t & 63, wid = t >> 6;
  const int b = blockIdx.x;

  {  // prefix: sum of cnt[0 .. b*1024)
    int pre = 0;
    for (int j = t; j < b * 1024; j += 1024) pre += cnt[j];
    #pragma unroll
    for (int m = 1; m <= 32; m <<= 1) pre += __shfl_xor(pre, m);
    if (lane == 0) wsum[wid] = pre;
    __syncthreads();
    if (t == 0) {
      int s = 0;
      #pragma unroll
      for (int j = 0; j < 16; j++) s += wsum[j];
      boff_s = s;
    }
    __syncthreads();
  }

  const int i = b * 1024 + t;
  const int val = (i < NN) ? cnt[i] : 0;
  int incl = val;
  #pragma unroll
  for (int off = 1; off < 64; off <<= 1) {
    int n = __shfl_up(incl, off, 64);
    if (lane >= off) incl += n;
  }
  if (lane == 63) wsum[wid] = incl;
  __syncthreads();
  if (t < 16) {
    int wv = wsum[t];
    int wincl = wv;
    #pragma unroll
    for (int off = 1; off < 16; off <<= 1) {
      int n = __shfl_up(wincl, off, 64);
      if (t >= off) wincl += n;
    }
    wsum[t] = wincl - wv;
  }
  __syncthreads();
  if (i < NN) {
    const int inc_g = boff_s + wsum[wid] + incl;   // inclusive global
    rowptr[i] = inc_g - val;                        // exclusive
    cntW[i]   = inc_g;                              // = rowptr[i+1], for fill
  }
  if (b == 0 && t == 0) rowptr[NN] = NE;
}

// ---------------- S3: bucket-fill, 4B records {src:16 | ea_fp16:16} ---------
__global__ __launch_bounds__(256) void k_fill(
    const int* __restrict__ ei, const float* __restrict__ ea,
    int* __restrict__ cntW, unsigned* __restrict__ epk) {
  const int e = blockIdx.x * 256 + threadIdx.x;
  if (e < NE) {
    const int dst = ei[NE + e];
    const int idx = atomicSub(&cntW[dst], 1) - 1;
    const unsigned rec = (unsigned)ei[e] |
        ((unsigned)__half_as_ushort(__float2half_rn(ea[e])) << 16);
    epk[idx] = rec;
  }
}

// ------- K2: per-dst softmax + agg (fp8 kv, DPP reduce, 8-edge unroll),
//         single barrier after wlT staging; waves independent afterwards -----
__global__ __launch_bounds__(256) void k_fused(
    const float* __restrict__ qs, const unsigned* __restrict__ kvp,
    const float* __restrict__ skip, const float* __restrict__ x,
    const int* __restrict__ rowptr, const unsigned* __restrict__ epk,
    const float* __restrict__ We,
    const float* __restrict__ Wl, const float* __restrict__ bl,
    const float* __restrict__ g0, const float* __restrict__ b0,
    const float* __restrict__ g1, const float* __restrict__ b1,
    float* __restrict__ out)
{
  __shared__ float wlT[64][65];   // wlT[k][j] = Wl[j][k]
  __shared__ float scx[4][64];    // per-wave scratch (transpose + x1 broadcast)
  const int t = threadIdx.x;
  {
    const int jl = t >> 2, c0 = (t & 3) * 16;
    const float4* wr = (const float4*)(Wl + (size_t)jl * 64 + c0);
    float4 w0 = wr[0], w1 = wr[1], w2 = wr[2], w3 = wr[3];
    wlT[c0 +  0][jl] = w0.x; wlT[c0 +  1][jl] = w0.y; wlT[c0 +  2][jl] = w0.z; wlT[c0 +  3][jl] = w0.w;
    wlT[c0 +  4][jl] = w1.x; wlT[c0 +  5][jl] = w1.y; wlT[c0 +  6][jl] = w1.z; wlT[c0 +  7][jl] = w1.w;
    wlT[c0 +  8][jl] = w2.x; wlT[c0 +  9][jl] = w2.y; wlT[c0 + 10][jl] = w2.z; wlT[c0 + 11][jl] = w2.w;
    wlT[c0 + 12][jl] = w3.x; wlT[c0 + 13][jl] = w3.y; wlT[c0 + 14][jl] = w3.z; wlT[c0 + 15][jl] = w3.w;
  }
  __syncthreads();  // the ONLY barrier

  const int w = t >> 6;
  const int dst = __builtin_amdgcn_readfirstlane(blockIdx.x * 4 + w);
  const int lane = t & 63;
  const int half = lane >> 5;
  const int el = lane & 31;

  const float4 qv = ((const float4*)(qs + (size_t)dst * 128))[el];
  const float4 we4 = ((const float4*)We)[el];
  const float skipv = skip[(size_t)dst * 64 + lane];
  const float xv    = x[(size_t)dst * 64 + lane];

  const float qwe = red16(qv.x * we4.x + qv.y * we4.y + qv.z * we4.z + qv.w * we4.w);

  const int base = rowptr[dst];
  const int deg  = rowptr[dst + 1] - base;
  const uint2* kv8 = (const uint2*)kvp;
  const unsigned* ep = epk + base;

  float s = 0.f, sw = 0.f;
  float sv0 = 0.f, sv1 = 0.f, sv2 = 0.f, sv3 = 0.f;

  const float SCL = 0.18033688011112042f;  // 0.125*log2(e)

#define UNPACK_W(er) __half2float(__ushort_as_half((unsigned short)((er) >> 16)))
#define PROC(u, wg, mask)                                                   \
  {                                                                         \
    const v2f k01 = __builtin_amdgcn_cvt_pk_f32_fp8((u).x, false);          \
    const v2f k23 = __builtin_amdgcn_cvt_pk_f32_fp8((u).x, true);           \
    const v2f v01 = __builtin_amdgcn_cvt_pk_f32_fp8((u).y, false);          \
    const v2f v23 = __builtin_amdgcn_cvt_pk_f32_fp8((u).y, true);           \
    const float p = red16(qv.x * k01.x + qv.y * k01.y +                     \
                          qv.z * k23.x + qv.w * k23.y);                     \
    float e_ = exp2f((p + (wg) * qwe) * SCL);                               \
    e_ = (mask) ? e_ : 0.f;                                                 \
    s += e_; sw += e_ * (wg);                                               \
    sv0 += e_ * v01.x; sv1 += e_ * v01.y;                                   \
    sv2 += e_ * v23.x; sv3 += e_ * v23.y;                                   \
  }

  int i = 0;
  for (; i + 8 <= deg; i += 8) {
    const unsigned er0 = ep[i + half];
    const unsigned er1 = ep[i + 2 + half];
    const unsigned er2 = ep[i + 4 + half];
    const unsigned er3 = ep[i + 6 + half];
    const uint2 u0 = kv8[(size_t)(er0 & 0xFFFFu) * 32 + el];
    const uint2 u1 = kv8[(size_t)(er1 & 0xFFFFu) * 32 + el];
    const uint2 u2 = kv8[(size_t)(er2 & 0xFFFFu) * 32 + el];
    const uint2 u3 = kv8[(size_t)(er3 & 0xFFFFu) * 32 + el];
    PROC(u0, UNPACK_W(er0), true)
    PROC(u1, UNPACK_W(er1), true)
    PROC(u2, UNPACK_W(er2), true)
    PROC(u3, UNPACK_W(er3), true)
  }
  for (; i + 4 <= deg; i += 4) {
    const unsigned er0 = ep[i + half];
    const unsigned er1 = ep[i + 2 + half];
    const uint2 u0 = kv8[(size_t)(er0 & 0xFFFFu) * 32 + el];
    const uint2 u1 = kv8[(size_t)(er1 & 0xFFFFu) * 32 + el];
    PROC(u0, UNPACK_W(er0), true)
    PROC(u1, UNPACK_W(er1), true)
  }
  for (; i < deg; i += 2) {
    const int idx = i + half;
    const bool valid = idx < deg;
    const unsigned er = ep[valid ? idx : (deg - 1)];
    const uint2 u = kv8[(size_t)(er & 0xFFFFu) * 32 + el];
    PROC(u, UNPACK_W(er), valid)
  }
#undef PROC
#undef UNPACK_W

  s  += __shfl_xor(s, 32);
  sw += __shfl_xor(sw, 32);
  sv0 += __shfl_xor(sv0, 32); sv1 += __shfl_xor(sv1, 32);
  sv2 += __shfl_xor(sv2, 32); sv3 += __shfl_xor(sv3, 32);

  float a0 = 0.f, a1 = 0.f, a2 = 0.f, a3 = 0.f;
  if (deg > 0) {
    const float inv = 1.f / s;
    a0 = (sv0 + sw * we4.x) * inv;
    a1 = (sv1 + sw * we4.y) * inv;
    a2 = (sv2 + sw * we4.z) * inv;
    a3 = (sv3 + sw * we4.w) * inv;
  }
  a0 = 0.5f * (a0 + __shfl_xor(a0, 16));
  a1 = 0.5f * (a1 + __shfl_xor(a1, 16));
  a2 = 0.5f * (a2 + __shfl_xor(a2, 16));
  a3 = 0.5f * (a3 + __shfl_xor(a3, 16));
  if (half == 0 && el < 16) {
    ((float4*)scx[w])[el] = make_float4(a0, a1, a2, a3);
  }
  const float hv = scx[w][lane] + skipv;

  // LN0 via dual moments
  float m1 = hv, m2 = hv * hv;
  m1 = red16(m1); m2 = red16(m2);
  m1 += __shfl_xor(m1, 16); m2 += __shfl_xor(m2, 16);
  m1 += __shfl_xor(m1, 32); m2 += __shfl_xor(m2, 32);
  const float mean = m1 * (1.f / 64.f);
  const float var = fmaxf(m2 * (1.f / 64.f) - mean * mean, 0.f);
  const float x1 = xv + (hv - mean) * rsqrtf(var + 1e-5f) * g0[lane] + b0[lane];

  // y = x1 @ Wl^T + bl via per-wave LDS broadcast
  scx[w][lane] = x1;
  float y0 = 0.f, y1 = 0.f, y2 = 0.f, y3 = 0.f;
  #pragma unroll
  for (int kk = 0; kk < 64; kk += 4) {
    const float4 xb = *(const float4*)&scx[w][kk];
    y0 += xb.x * wlT[kk][lane];
    y1 += xb.y * wlT[kk + 1][lane];
    y2 += xb.z * wlT[kk + 2][lane];
    y3 += xb.w * wlT[kk + 3][lane];
  }
  const float y = bl[lane] + (y0 + y1) + (y2 + y3);

  // LN1 via dual moments
  float n1 = y, n2 = y * y;
  n1 = red16(n1); n2 = red16(n2);
  n1 += __shfl_xor(n1, 16); n2 += __shfl_xor(n2, 16);
  n1 += __shfl_xor(n1, 32); n2 += __shfl_xor(n2, 32);
  const float mean2 = n1 * (1.f / 64.f);
  const float var2 = fmaxf(n2 * (1.f / 64.f) - mean2 * mean2, 0.f);
  out[(size_t)dst * 64 + lane] = x1 + (y - mean2) * rsqrtf(var2 + 1e-5f) * g1[lane] + b1[lane];
}

extern "C" void kernel_launch(void* const* d_in, const int* in_sizes, int n_in,
                              void* d_out, int out_size, void* d_ws, size_t ws_size,
                              hipStream_t stream) {
  const float* x     = (const float*)d_in[0];
  const int*   ei    = (const int*)d_in[1];
  const float* ea    = (const float*)d_in[2];
  const float* Wq    = (const float*)d_in[3];
  const float* bq    = (const float*)d_in[4];
  const float* Wk    = (const float*)d_in[5];
  const float* bk    = (const float*)d_in[6];
  const float* Wv    = (const float*)d_in[7];
  const float* bv    = (const float*)d_in[8];
  const float* We    = (const float*)d_in[9];
  const float* Wskip = (const float*)d_in[10];
  const float* bskip = (const float*)d_in[11];
  const float* Wl    = (const float*)d_in[12];
  const float* bl    = (const float*)d_in[13];
  const float* g0    = (const float*)d_in[14];
  const float* b0    = (const float*)d_in[15];
  const float* g1    = (const float*)d_in[16];
  const float* b1    = (const float*)d_in[17];
  float* out = (float*)d_out;

  float* ws = (float*)d_ws;
  size_t off = 0;
  float* qs   = ws + off; off += (size_t)NN * 128;
  unsigned* kvp = (unsigned*)(ws + off); off += (size_t)NN * 64;  // 256B/node fp8
  float* skip = ws + off; off += (size_t)NN * 64;
  int* cnt    = (int*)(ws + off); off += NN;
  int* cntW   = (int*)(ws + off); off += NN;
  int* rowptr = (int*)(ws + off); off += NN + 1;
  unsigned* epk = (unsigned*)(ws + off); off += NE;

  (void)hipMemsetAsync(cnt, 0, (size_t)NN * sizeof(int), stream);

  dim3 gGemm((NN + 63) / 64, 2);  // y==1 -> histogram slice
  hipLaunchKernelGGL(k_gemm_qkv, gGemm, dim3(256), 0, stream,
                     x, Wq, bq, Wk, bk, Wv, bv, Wskip, bskip, ei, cnt, qs, kvp, skip);
  hipLaunchKernelGGL(k_scan, dim3(49), dim3(1024), 0, stream, cnt, rowptr, cntW);
  hipLaunchKernelGGL(k_fill, dim3((NE + 255) / 256), dim3(256), 0, stream,
                     ei, ea, cntW, epk);
  hipLaunchKernelGGL(k_fused, dim3(NN / 4), dim3(256), 0, stream,
                     qs, kvp, skip, x, rowptr, epk, We,
                     Wl, bl, g0, b0, g1, b1, out);
}

// Round 15
// 160.662 us; speedup vs baseline: 1.3024x; 1.1466x over previous
//
#include <hip/hip_runtime.h>
#include <hip/hip_fp16.h>

#define NN 50000
#define NE 800000

typedef unsigned short u16;
typedef float v2f __attribute__((ext_vector_type(2)));

// ---- 16-lane all-reduce on the VALU pipe via DPP (no DS ops) ----
template <int CTRL>
__device__ __forceinline__ float dpp_add(float p) {
  const int v = __builtin_amdgcn_update_dpp(0, __float_as_int(p), CTRL, 0xF, 0xF, true);
  return p + __int_as_float(v);
}
__device__ __forceinline__ float red16(float p) {
  p = dpp_add<0xB1>(p);   // quad_perm [1,0,3,2]
  p = dpp_add<0x4E>(p);   // quad_perm [2,3,0,1]
  p = dpp_add<0x141>(p);  // row_half_mirror
  p = dpp_add<0x140>(p);  // row_mirror
  return p;
}

// ---------------- K1: fused QKV + skip GEMM (64-tile) + histogram+pos ------
// slice order: 0:q0 1:q1 2:skip 3:k0 4:v0 5:k1 6:v1  (k stashed, kv written as pairs)
// q stored natural [n][128] fp32.
// kv stored [n][64] x u32 fp8-e4m3: entry e: k at 2e, v at 2e+1.
__global__ __launch_bounds__(256) void k_gemm_qkv(
    const float* __restrict__ x,
    const float* __restrict__ Wq, const float* __restrict__ bq,
    const float* __restrict__ Wk, const float* __restrict__ bk,
    const float* __restrict__ Wv, const float* __restrict__ bv,
    const float* __restrict__ Wskip, const float* __restrict__ bskip,
    const int* __restrict__ ei, int* __restrict__ cnt, int* __restrict__ pos,
    float* __restrict__ qs, unsigned* __restrict__ kvp, float* __restrict__ skip)
{
  const int t = threadIdx.x;

  if (blockIdx.y == 1) {  // histogram slice (+ per-edge bucket position)
    const int e0 = blockIdx.x * 1024 + t;
    #pragma unroll
    for (int it = 0; it < 4; it++) {
      const int e = e0 + it * 256;
      if (e < NE) pos[e] = atomicAdd(&cnt[ei[NE + e]], 1);
    }
    return;
  }

  __shared__ float xsT[64][68];
  __shared__ float wsT[64][68];
  const int tileN = blockIdx.x * 64;

  {  // load x tile once
    const int nl = t >> 2, c0 = (t & 3) * 16;
    const int n = tileN + nl;
    float4 a0, a1, a2, a3;
    if (n < NN) {
      const float4* xr = (const float4*)(x + (size_t)n * 64 + c0);
      a0 = xr[0]; a1 = xr[1]; a2 = xr[2]; a3 = xr[3];
    } else {
      a0 = a1 = a2 = a3 = make_float4(0.f, 0.f, 0.f, 0.f);
    }
    xsT[c0 +  0][nl] = a0.x; xsT[c0 +  1][nl] = a0.y; xsT[c0 +  2][nl] = a0.z; xsT[c0 +  3][nl] = a0.w;
    xsT[c0 +  4][nl] = a1.x; xsT[c0 +  5][nl] = a1.y; xsT[c0 +  6][nl] = a1.z; xsT[c0 +  7][nl] = a1.w;
    xsT[c0 +  8][nl] = a2.x; xsT[c0 +  9][nl] = a2.y; xsT[c0 + 10][nl] = a2.z; xsT[c0 + 11][nl] = a2.w;
    xsT[c0 + 12][nl] = a3.x; xsT[c0 + 13][nl] = a3.y; xsT[c0 + 14][nl] = a3.z; xsT[c0 + 15][nl] = a3.w;
  }

  const int tx = t & 15, ty = t >> 4;
  unsigned kst0 = 0, kst1 = 0, kst2 = 0, kst3 = 0;  // stashed packed k rows

  for (int step = 0; step < 7; step++) {
    // slice decode: kind 0=q,1=skip,2=k,3=v
    const float* W; const float* bias; int rowbase; int kind;
    if (step == 0)      { W = Wq;    bias = bq;        rowbase = 0;  kind = 0; }
    else if (step == 1) { W = Wq + 64 * 64;  bias = bq + 64; rowbase = 64; kind = 0; }
    else if (step == 2) { W = Wskip; bias = bskip;     rowbase = 0;  kind = 1; }
    else if (step == 3) { W = Wk;    bias = bk;        rowbase = 0;  kind = 2; }
    else if (step == 4) { W = Wv;    bias = bv;        rowbase = 0;  kind = 3; }
    else if (step == 5) { W = Wk + 64 * 64;  bias = bk + 64; rowbase = 64; kind = 2; }
    else                { W = Wv + 64 * 64;  bias = bv + 64; rowbase = 64; kind = 3; }
    // NOTE: W rows rowbase..rowbase+63 == W + rowbase*64 (contiguous); for the
    // +64-row slices we pass W+64*64 and use local rows 0..63.

    __syncthreads();
    {
      const int nl = t >> 2, c0 = (t & 3) * 16;
      const float4* wr = (const float4*)(W + (size_t)nl * 64 + c0);
      float4 b0 = wr[0], b1 = wr[1], b2 = wr[2], b3 = wr[3];
      wsT[c0 +  0][nl] = b0.x; wsT[c0 +  1][nl] = b0.y; wsT[c0 +  2][nl] = b0.z; wsT[c0 +  3][nl] = b0.w;
      wsT[c0 +  4][nl] = b1.x; wsT[c0 +  5][nl] = b1.y; wsT[c0 +  6][nl] = b1.z; wsT[c0 +  7][nl] = b1.w;
      wsT[c0 +  8][nl] = b2.x; wsT[c0 +  9][nl] = b2.y; wsT[c0 + 10][nl] = b2.z; wsT[c0 + 11][nl] = b2.w;
      wsT[c0 + 12][nl] = b3.x; wsT[c0 + 13][nl] = b3.y; wsT[c0 + 14][nl] = b3.z; wsT[c0 + 15][nl] = b3.w;
    }
    __syncthreads();

    float acc[4][4];
    #pragma unroll
    for (int i = 0; i < 4; i++)
      #pragma unroll
      for (int j = 0; j < 4; j++) acc[i][j] = 0.f;

    #pragma unroll 8
    for (int kk = 0; kk < 64; kk++) {
      float4 a = *(const float4*)&xsT[kk][tx * 4];
      float4 b = *(const float4*)&wsT[kk][ty * 4];
      acc[0][0] += a.x * b.x; acc[0][1] += a.x * b.y; acc[0][2] += a.x * b.z; acc[0][3] += a.x * b.w;
      acc[1][0] += a.y * b.x; acc[1][1] += a.y * b.y; acc[1][2] += a.y * b.z; acc[1][3] += a.y * b.w;
      acc[2][0] += a.z * b.x; acc[2][1] += a.z * b.y; acc[2][2] += a.z * b.z; acc[2][3] += a.z * b.w;
      acc[3][0] += a.w * b.x; acc[3][1] += a.w * b.y; acc[3][2] += a.w * b.z; acc[3][3] += a.w * b.w;
    }

    const int n0 = tileN + tx * 4;
    const int col0 = rowbase + ty * 4;
    const float4 bb = *(const float4*)(bias + ty * 4);
    #pragma unroll
    for (int i = 0; i < 4; i++) {
      const int n = n0 + i;
      const bool ok = (n < NN);
      const float r0 = acc[i][0] + bb.x, r1 = acc[i][1] + bb.y;
      const float r2 = acc[i][2] + bb.z, r3 = acc[i][3] + bb.w;
      if (kind == 0) {
        if (ok) *(float4*)(qs + (size_t)n * 128 + col0) = make_float4(r0, r1, r2, r3);
      } else if (kind == 1) {
        if (ok) *(float4*)(skip + (size_t)n * 64 + col0) = make_float4(r0, r1, r2, r3);
      } else if (kind == 2) {
        unsigned pk = 0;
        pk = __builtin_amdgcn_cvt_pk_fp8_f32(r0, r1, pk, false);
        pk = __builtin_amdgcn_cvt_pk_fp8_f32(r2, r3, pk, true);
        if (i == 0) kst0 = pk; else if (i == 1) kst1 = pk;
        else if (i == 2) kst2 = pk; else kst3 = pk;
      } else {
        unsigned pv = 0;
        pv = __builtin_amdgcn_cvt_pk_fp8_f32(r0, r1, pv, false);
        pv = __builtin_amdgcn_cvt_pk_fp8_f32(r2, r3, pv, true);
        const unsigned kw = (i == 0) ? kst0 : (i == 1) ? kst1 : (i == 2) ? kst2 : kst3;
        const int entry = col0 >> 2;
        if (ok) *(uint2*)(kvp + (size_t)n * 64 + entry * 2) = make_uint2(kw, pv);
      }
    }
  }
}

// ---------------- S2: single merged scan (49 blocks; self-computed prefix) --
__global__ __launch_bounds__(1024) void k_scan(
    const int* __restrict__ cnt, int* __restrict__ rowptr) {
  __shared__ int wsum[16];
  __shared__ int boff_s;
  const int t = threadIdx.x, lane = t & 63, wid = t >> 6;
  const int b = blockIdx.x;

  {  // prefix: sum of cnt[0 .. b*1024)
    int pre = 0;
    for (int j = t; j < b * 1024; j += 1024) pre += cnt[j];
    #pragma unroll
    for (int m = 1; m <= 32; m <<= 1) pre += __shfl_xor(pre, m);
    if (lane == 0) wsum[wid] = pre;
    __syncthreads();
    if (t == 0) {
      int s = 0;
      #pragma unroll
      for (int j = 0; j < 16; j++) s += wsum[j];
      boff_s = s;
    }
    __syncthreads();
  }

  const int i = b * 1024 + t;
  const int val = (i < NN) ? cnt[i] : 0;
  int incl = val;
  #pragma unroll
  for (int off = 1; off < 64; off <<= 1) {
    int n = __shfl_up(incl, off, 64);
    if (lane >= off) incl += n;
  }
  if (lane == 63) wsum[wid] = incl;
  __syncthreads();
  if (t < 16) {
    int wv = wsum[t];
    int wincl = wv;
    #pragma unroll
    for (int off = 1; off < 16; off <<= 1) {
      int n = __shfl_up(wincl, off, 64);
      if (t >= off) wincl += n;
    }
    wsum[t] = wincl - wv;
  }
  __syncthreads();
  if (i < NN) rowptr[i] = boff_s + wsum[wid] + incl - val;
  if (b == 0 && t == 0) rowptr[NN] = NE;
}

// ---------------- S3: pure scatter fill (no atomics), 4B records ------------
__global__ __launch_bounds__(256) void k_fill(
    const int* __restrict__ ei, const float* __restrict__ ea,
    const int* __restrict__ rowptr, const int* __restrict__ pos,
    unsigned* __restrict__ epk) {
  const int e = blockIdx.x * 256 + threadIdx.x;
  if (e < NE) {
    const int dst = ei[NE + e];
    const int idx = rowptr[dst] + pos[e];
    const unsigned rec = (unsigned)ei[e] |
        ((unsigned)__half_as_ushort(__float2half_rn(ea[e])) << 16);
    epk[idx] = rec;
  }
}

// ------- K2: per-dst softmax + agg (fp8 kv, DPP reduce, 8-edge unroll),
//         single barrier after wlT staging; waves independent afterwards -----
__global__ __launch_bounds__(256) void k_fused(
    const float* __restrict__ qs, const unsigned* __restrict__ kvp,
    const float* __restrict__ skip, const float* __restrict__ x,
    const int* __restrict__ rowptr, const unsigned* __restrict__ epk,
    const float* __restrict__ We,
    const float* __restrict__ Wl, const float* __restrict__ bl,
    const float* __restrict__ g0, const float* __restrict__ b0,
    const float* __restrict__ g1, const float* __restrict__ b1,
    float* __restrict__ out)
{
  __shared__ float wlT[64][65];   // wlT[k][j] = Wl[j][k]
  __shared__ float scx[4][64];    // per-wave scratch (transpose + x1 broadcast)
  const int t = threadIdx.x;
  {
    const int jl = t >> 2, c0 = (t & 3) * 16;
    const float4* wr = (const float4*)(Wl + (size_t)jl * 64 + c0);
    float4 w0 = wr[0], w1 = wr[1], w2 = wr[2], w3 = wr[3];
    wlT[c0 +  0][jl] = w0.x; wlT[c0 +  1][jl] = w0.y; wlT[c0 +  2][jl] = w0.z; wlT[c0 +  3][jl] = w0.w;
    wlT[c0 +  4][jl] = w1.x; wlT[c0 +  5][jl] = w1.y; wlT[c0 +  6][jl] = w1.z; wlT[c0 +  7][jl] = w1.w;
    wlT[c0 +  8][jl] = w2.x; wlT[c0 +  9][jl] = w2.y; wlT[c0 + 10][jl] = w2.z; wlT[c0 + 11][jl] = w2.w;
    wlT[c0 + 12][jl] = w3.x; wlT[c0 + 13][jl] = w3.y; wlT[c0 + 14][jl] = w3.z; wlT[c0 + 15][jl] = w3.w;
  }
  __syncthreads();  // the ONLY barrier

  const int w = t >> 6;
  const int dst = __builtin_amdgcn_readfirstlane(blockIdx.x * 4 + w);
  const int lane = t & 63;
  const int half = lane >> 5;
  const int el = lane & 31;

  const float4 qv = ((const float4*)(qs + (size_t)dst * 128))[el];
  const float4 we4 = ((const float4*)We)[el];
  const float skipv = skip[(size_t)dst * 64 + lane];
  const float xv    = x[(size_t)dst * 64 + lane];

  const float qwe = red16(qv.x * we4.x + qv.y * we4.y + qv.z * we4.z + qv.w * we4.w);

  const int base = rowptr[dst];
  const int deg  = rowptr[dst + 1] - base;
  const uint2* kv8 = (const uint2*)kvp;
  const unsigned* ep = epk + base;

  float s = 0.f, sw = 0.f;
  float sv0 = 0.f, sv1 = 0.f, sv2 = 0.f, sv3 = 0.f;

  const float SCL = 0.18033688011112042f;  // 0.125*log2(e)

#define UNPACK_W(er) __half2float(__ushort_as_half((unsigned short)((er) >> 16)))
#define PROC(u, wg, mask)                                                   \
  {                                                                         \
    const v2f k01 = __builtin_amdgcn_cvt_pk_f32_fp8((u).x, false);          \
    const v2f k23 = __builtin_amdgcn_cvt_pk_f32_fp8((u).x, true);           \
    const v2f v01 = __builtin_amdgcn_cvt_pk_f32_fp8((u).y, false);          \
    const v2f v23 = __builtin_amdgcn_cvt_pk_f32_fp8((u).y, true);           \
    const float p = red16(qv.x * k01.x + qv.y * k01.y +                     \
                          qv.z * k23.x + qv.w * k23.y);                     \
    float e_ = exp2f((p + (wg) * qwe) * SCL);                               \
    e_ = (mask) ? e_ : 0.f;                                                 \
    s += e_; sw += e_ * (wg);                                               \
    sv0 += e_ * v01.x; sv1 += e_ * v01.y;                                   \
    sv2 += e_ * v23.x; sv3 += e_ * v23.y;                                   \
  }

  int i = 0;
  for (; i + 8 <= deg; i += 8) {
    const unsigned er0 = ep[i + half];
    const unsigned er1 = ep[i + 2 + half];
    const unsigned er2 = ep[i + 4 + half];
    const unsigned er3 = ep[i + 6 + half];
    const uint2 u0 = kv8[(size_t)(er0 & 0xFFFFu) * 32 + el];
    const uint2 u1 = kv8[(size_t)(er1 & 0xFFFFu) * 32 + el];
    const uint2 u2 = kv8[(size_t)(er2 & 0xFFFFu) * 32 + el];
    const uint2 u3 = kv8[(size_t)(er3 & 0xFFFFu) * 32 + el];
    PROC(u0, UNPACK_W(er0), true)
    PROC(u1, UNPACK_W(er1), true)
    PROC(u2, UNPACK_W(er2), true)
    PROC(u3, UNPACK_W(er3), true)
  }
  for (; i + 4 <= deg; i += 4) {
    const unsigned er0 = ep[i + half];
    const unsigned er1 = ep[i + 2 + half];
    const uint2 u0 = kv8[(size_t)(er0 & 0xFFFFu) * 32 + el];
    const uint2 u1 = kv8[(size_t)(er1 & 0xFFFFu) * 32 + el];
    PROC(u0, UNPACK_W(er0), true)
    PROC(u1, UNPACK_W(er1), true)
  }
  for (; i < deg; i += 2) {
    const int idx = i + half;
    const bool valid = idx < deg;
    const unsigned er = ep[valid ? idx : (deg - 1)];
    const uint2 u = kv8[(size_t)(er & 0xFFFFu) * 32 + el];
    PROC(u, UNPACK_W(er), valid)
  }
#undef PROC
#undef UNPACK_W

  s  += __shfl_xor(s, 32);
  sw += __shfl_xor(sw, 32);
  sv0 += __shfl_xor(sv0, 32); sv1 += __shfl_xor(sv1, 32);
  sv2 += __shfl_xor(sv2, 32); sv3 += __shfl_xor(sv3, 32);

  float a0 = 0.f, a1 = 0.f, a2 = 0.f, a3 = 0.f;
  if (deg > 0) {
    const float inv = 1.f / s;
    a0 = (sv0 + sw * we4.x) * inv;
    a1 = (sv1 + sw * we4.y) * inv;
    a2 = (sv2 + sw * we4.z) * inv;
    a3 = (sv3 + sw * we4.w) * inv;
  }
  a0 = 0.5f * (a0 + __shfl_xor(a0, 16));
  a1 = 0.5f * (a1 + __shfl_xor(a1, 16));
  a2 = 0.5f * (a2 + __shfl_xor(a2, 16));
  a3 = 0.5f * (a3 + __shfl_xor(a3, 16));
  if (half == 0 && el < 16) {
    ((float4*)scx[w])[el] = make_float4(a0, a1, a2, a3);
  }
  const float hv = scx[w][lane] + skipv;

  // LN0 via dual moments
  float m1 = hv, m2 = hv * hv;
  m1 = red16(m1); m2 = red16(m2);
  m1 += __shfl_xor(m1, 16); m2 += __shfl_xor(m2, 16);
  m1 += __shfl_xor(m1, 32); m2 += __shfl_xor(m2, 32);
  const float mean = m1 * (1.f / 64.f);
  const float var = fmaxf(m2 * (1.f / 64.f) - mean * mean, 0.f);
  const float x1 = xv + (hv - mean) * rsqrtf(var + 1e-5f) * g0[lane] + b0[lane];

  // y = x1 @ Wl^T + bl via per-wave LDS broadcast
  scx[w][lane] = x1;
  float y0 = 0.f, y1 = 0.f, y2 = 0.f, y3 = 0.f;
  #pragma unroll
  for (int kk = 0; kk < 64; kk += 4) {
    const float4 xb = *(const float4*)&scx[w][kk];
    y0 += xb.x * wlT[kk][lane];
    y1 += xb.y * wlT[kk + 1][lane];
    y2 += xb.z * wlT[kk + 2][lane];
    y3 += xb.w * wlT[kk + 3][lane];
  }
  const float y = bl[lane] + (y0 + y1) + (y2 + y3);

  // LN1 via dual moments
  float n1 = y, n2 = y * y;
  n1 = red16(n1); n2 = red16(n2);
  n1 += __shfl_xor(n1, 16); n2 += __shfl_xor(n2, 16);
  n1 += __shfl_xor(n1, 32); n2 += __shfl_xor(n2, 32);
  const float mean2 = n1 * (1.f / 64.f);
  const float var2 = fmaxf(n2 * (1.f / 64.f) - mean2 * mean2, 0.f);
  out[(size_t)dst * 64 + lane] = x1 + (y - mean2) * rsqrtf(var2 + 1e-5f) * g1[lane] + b1[lane];
}

extern "C" void kernel_launch(void* const* d_in, const int* in_sizes, int n_in,
                              void* d_out, int out_size, void* d_ws, size_t ws_size,
                              hipStream_t stream) {
  const float* x     = (const float*)d_in[0];
  const int*   ei    = (const int*)d_in[1];
  const float* ea    = (const float*)d_in[2];
  const float* Wq    = (const float*)d_in[3];
  const float* bq    = (const float*)d_in[4];
  const float* Wk    = (const float*)d_in[5];
  const float* bk    = (const float*)d_in[6];
  const float* Wv    = (const float*)d_in[7];
  const float* bv    = (const float*)d_in[8];
  const float* We    = (const float*)d_in[9];
  const float* Wskip = (const float*)d_in[10];
  const float* bskip = (const float*)d_in[11];
  const float* Wl    = (const float*)d_in[12];
  const float* bl    = (const float*)d_in[13];
  const float* g0    = (const float*)d_in[14];
  const float* b0    = (const float*)d_in[15];
  const float* g1    = (const float*)d_in[16];
  const float* b1    = (const float*)d_in[17];
  float* out = (float*)d_out;

  float* ws = (float*)d_ws;
  size_t off = 0;
  float* qs   = ws + off; off += (size_t)NN * 128;
  unsigned* kvp = (unsigned*)(ws + off); off += (size_t)NN * 64;  // 256B/node fp8
  float* skip = ws + off; off += (size_t)NN * 64;
  int* cnt    = (int*)(ws + off); off += NN;
  int* rowptr = (int*)(ws + off); off += NN + 1;
  int* pos    = (int*)(ws + off); off += NE;
  unsigned* epk = (unsigned*)(ws + off); off += NE;

  (void)hipMemsetAsync(cnt, 0, (size_t)NN * sizeof(int), stream);

  dim3 gGemm((NN + 63) / 64, 2);  // y==1 -> histogram+pos slice
  hipLaunchKernelGGL(k_gemm_qkv, gGemm, dim3(256), 0, stream,
                     x, Wq, bq, Wk, bk, Wv, bv, Wskip, bskip, ei, cnt, pos, qs, kvp, skip);
  hipLaunchKernelGGL(k_scan, dim3(49), dim3(1024), 0, stream, cnt, rowptr);
  hipLaunchKernelGGL(k_fill, dim3((NE + 255) / 256), dim3(256), 0, stream,
                     ei, ea, rowptr, pos, epk);
  hipLaunchKernelGGL(k_fused, dim3(NN / 4), dim3(256), 0, stream,
                     qs, kvp, skip, x, rowptr, epk, We,
                     Wl, bl, g0, b0, g1, b1, out);
}

// Round 16
// 150.741 us; speedup vs baseline: 1.3881x; 1.0658x over previous
//
#include <hip/hip_runtime.h>
#include <hip/hip_fp16.h>

#define NN 50000
#define NE 800000

typedef unsigned short u16;
typedef float v2f __attribute__((ext_vector_type(2)));

// ---- 16-lane all-reduce on the VALU pipe via DPP (no DS ops) ----
template <int CTRL>
__device__ __forceinline__ float dpp_add(float p) {
  const int v = __builtin_amdgcn_update_dpp(0, __float_as_int(p), CTRL, 0xF, 0xF, true);
  return p + __int_as_float(v);
}
__device__ __forceinline__ float red16(float p) {
  p = dpp_add<0xB1>(p);   // quad_perm [1,0,3,2]
  p = dpp_add<0x4E>(p);   // quad_perm [2,3,0,1]
  p = dpp_add<0x141>(p);  // row_half_mirror
  p = dpp_add<0x140>(p);  // row_mirror
  return p;
}

// ---------------- K1: fused QKV + skip GEMM, y-split slices + histogram -----
// y=0: slices {q0,q1,skip}; y=1: slices {k0,k1,v0,v1}; y=2: histogram+pos
// q stored natural [n][128] fp32.
// kv stored [n][64] x u32 fp8-e4m3: entry e: k at 2e, v at 2e+1.
__global__ __launch_bounds__(256) void k_gemm_qkv(
    const float* __restrict__ x,
    const float* __restrict__ Wq, const float* __restrict__ bq,
    const float* __restrict__ Wk, const float* __restrict__ bk,
    const float* __restrict__ Wv, const float* __restrict__ bv,
    const float* __restrict__ Wskip, const float* __restrict__ bskip,
    const int* __restrict__ ei, int* __restrict__ cnt, int* __restrict__ pos,
    float* __restrict__ qs, unsigned* __restrict__ kvp, float* __restrict__ skip)
{
  const int t = threadIdx.x;
  const int y = blockIdx.y;

  if (y == 2) {  // histogram slice (+ per-edge bucket position)
    const int e0 = blockIdx.x * 1024 + t;
    #pragma unroll
    for (int it = 0; it < 4; it++) {
      const int e = e0 + it * 256;
      if (e < NE) pos[e] = atomicAdd(&cnt[ei[NE + e]], 1);
    }
    return;
  }

  __shared__ float xsT[64][68];
  __shared__ float wsT[64][68];
  const int tileN = blockIdx.x * 64;

  {  // load x tile once
    const int nl = t >> 2, c0 = (t & 3) * 16;
    const int n = tileN + nl;
    float4 a0, a1, a2, a3;
    if (n < NN) {
      const float4* xr = (const float4*)(x + (size_t)n * 64 + c0);
      a0 = xr[0]; a1 = xr[1]; a2 = xr[2]; a3 = xr[3];
    } else {
      a0 = a1 = a2 = a3 = make_float4(0.f, 0.f, 0.f, 0.f);
    }
    xsT[c0 +  0][nl] = a0.x; xsT[c0 +  1][nl] = a0.y; xsT[c0 +  2][nl] = a0.z; xsT[c0 +  3][nl] = a0.w;
    xsT[c0 +  4][nl] = a1.x; xsT[c0 +  5][nl] = a1.y; xsT[c0 +  6][nl] = a1.z; xsT[c0 +  7][nl] = a1.w;
    xsT[c0 +  8][nl] = a2.x; xsT[c0 +  9][nl] = a2.y; xsT[c0 + 10][nl] = a2.z; xsT[c0 + 11][nl] = a2.w;
    xsT[c0 + 12][nl] = a3.x; xsT[c0 + 13][nl] = a3.y; xsT[c0 + 14][nl] = a3.z; xsT[c0 + 15][nl] = a3.w;
  }

  const int tx = t & 15, ty = t >> 4;
  const int nslices = (y == 0) ? 3 : 4;

  for (int s = 0; s < nslices; s++) {
    // y=0: jt = 0,1,6 (q0,q1,skip); y=1: jt = 2,3,4,5 (k0,k1,v0,v1)
    const int jt = (y == 0) ? ((s == 2) ? 6 : s) : (s + 2);
    const float* W; const float* bias; int rowbase;
    if (jt < 2)      { W = Wq;    bias = bq;    rowbase = jt * 64; }
    else if (jt < 4) { W = Wk;    bias = bk;    rowbase = (jt - 2) * 64; }
    else if (jt < 6) { W = Wv;    bias = bv;    rowbase = (jt - 4) * 64; }
    else             { W = Wskip; bias = bskip; rowbase = 0; }

    __syncthreads();
    {
      const int nl = t >> 2, c0 = (t & 3) * 16;
      const float4* wr = (const float4*)(W + (size_t)(rowbase + nl) * 64 + c0);
      float4 b0 = wr[0], b1 = wr[1], b2 = wr[2], b3 = wr[3];
      wsT[c0 +  0][nl] = b0.x; wsT[c0 +  1][nl] = b0.y; wsT[c0 +  2][nl] = b0.z; wsT[c0 +  3][nl] = b0.w;
      wsT[c0 +  4][nl] = b1.x; wsT[c0 +  5][nl] = b1.y; wsT[c0 +  6][nl] = b1.z; wsT[c0 +  7][nl] = b1.w;
      wsT[c0 +  8][nl] = b2.x; wsT[c0 +  9][nl] = b2.y; wsT[c0 + 10][nl] = b2.z; wsT[c0 + 11][nl] = b2.w;
      wsT[c0 + 12][nl] = b3.x; wsT[c0 + 13][nl] = b3.y; wsT[c0 + 14][nl] = b3.z; wsT[c0 + 15][nl] = b3.w;
    }
    __syncthreads();

    float acc[4][4];
    #pragma unroll
    for (int i = 0; i < 4; i++)
      #pragma unroll
      for (int j = 0; j < 4; j++) acc[i][j] = 0.f;

    #pragma unroll 8
    for (int kk = 0; kk < 64; kk++) {
      float4 a = *(const float4*)&xsT[kk][tx * 4];
      float4 b = *(const float4*)&wsT[kk][ty * 4];
      acc[0][0] += a.x * b.x; acc[0][1] += a.x * b.y; acc[0][2] += a.x * b.z; acc[0][3] += a.x * b.w;
      acc[1][0] += a.y * b.x; acc[1][1] += a.y * b.y; acc[1][2] += a.y * b.z; acc[1][3] += a.y * b.w;
      acc[2][0] += a.z * b.x; acc[2][1] += a.z * b.y; acc[2][2] += a.z * b.z; acc[2][3] += a.z * b.w;
      acc[3][0] += a.w * b.x; acc[3][1] += a.w * b.y; acc[3][2] += a.w * b.z; acc[3][3] += a.w * b.w;
    }

    const int n0 = tileN + tx * 4;
    const int col0 = rowbase + ty * 4;
    const float4 bb = *(const float4*)(bias + col0);
    #pragma unroll
    for (int i = 0; i < 4; i++) {
      const int n = n0 + i;
      if (n >= NN) continue;
      const float r0 = acc[i][0] + bb.x, r1 = acc[i][1] + bb.y;
      const float r2 = acc[i][2] + bb.z, r3 = acc[i][3] + bb.w;
      if (jt < 2) {
        *(float4*)(qs + (size_t)n * 128 + col0) = make_float4(r0, r1, r2, r3);
      } else if (jt < 6) {
        const int entry = col0 >> 2;
        unsigned pk = 0;
        pk = __builtin_amdgcn_cvt_pk_fp8_f32(r0, r1, pk, false);
        pk = __builtin_amdgcn_cvt_pk_fp8_f32(r2, r3, pk, true);
        kvp[(size_t)n * 64 + entry * 2 + ((jt >= 4) ? 1 : 0)] = pk;
      } else {
        *(float4*)(skip + (size_t)n * 64 + col0) = make_float4(r0, r1, r2, r3);
      }
    }
  }
}

// ---------------- S2: single merged scan (49 blocks; self-computed prefix) --
__global__ __launch_bounds__(1024) void k_scan(
    const int* __restrict__ cnt, int* __restrict__ rowptr) {
  __shared__ int wsum[16];
  __shared__ int boff_s;
  const int t = threadIdx.x, lane = t & 63, wid = t >> 6;
  const int b = blockIdx.x;

  {  // prefix: sum of cnt[0 .. b*1024)
    int pre = 0;
    for (int j = t; j < b * 1024; j += 1024) pre += cnt[j];
    #pragma unroll
    for (int m = 1; m <= 32; m <<= 1) pre += __shfl_xor(pre, m);
    if (lane == 0) wsum[wid] = pre;
    __syncthreads();
    if (t == 0) {
      int s = 0;
      #pragma unroll
      for (int j = 0; j < 16; j++) s += wsum[j];
      boff_s = s;
    }
    __syncthreads();
  }

  const int i = b * 1024 + t;
  const int val = (i < NN) ? cnt[i] : 0;
  int incl = val;
  #pragma unroll
  for (int off = 1; off < 64; off <<= 1) {
    int n = __shfl_up(incl, off, 64);
    if (lane >= off) incl += n;
  }
  if (lane == 63) wsum[wid] = incl;
  __syncthreads();
  if (t < 16) {
    int wv = wsum[t];
    int wincl = wv;
    #pragma unroll
    for (int off = 1; off < 16; off <<= 1) {
      int n = __shfl_up(wincl, off, 64);
      if (t >= off) wincl += n;
    }
    wsum[t] = wincl - wv;
  }
  __syncthreads();
  if (i < NN) rowptr[i] = boff_s + wsum[wid] + incl - val;
  if (b == 0 && t == 0) rowptr[NN] = NE;
}

// ---------------- S3: pure scatter fill (no atomics), 4B records ------------
__global__ __launch_bounds__(256) void k_fill(
    const int* __restrict__ ei, const float* __restrict__ ea,
    const int* __restrict__ rowptr, const int* __restrict__ pos,
    unsigned* __restrict__ epk) {
  const int e = blockIdx.x * 256 + threadIdx.x;
  if (e < NE) {
    const int dst = ei[NE + e];
    const int idx = rowptr[dst] + pos[e];
    const unsigned rec = (unsigned)ei[e] |
        ((unsigned)__half_as_ushort(__float2half_rn(ea[e])) << 16);
    epk[idx] = rec;
  }
}

// ------- K2: per-dst softmax + agg (fp8 kv, DPP reduce, 8-edge unroll),
//         single barrier after wlT staging; waves independent afterwards -----
__global__ __launch_bounds__(256) void k_fused(
    const float* __restrict__ qs, const unsigned* __restrict__ kvp,
    const float* __restrict__ skip, const float* __restrict__ x,
    const int* __restrict__ rowptr, const unsigned* __restrict__ epk,
    const float* __restrict__ We,
    const float* __restrict__ Wl, const float* __restrict__ bl,
    const float* __restrict__ g0, const float* __restrict__ b0,
    const float* __restrict__ g1, const float* __restrict__ b1,
    float* __restrict__ out)
{
  __shared__ float wlT[64][65];   // wlT[k][j] = Wl[j][k]
  __shared__ float scx[4][64];    // per-wave scratch (transpose + x1 broadcast)
  const int t = threadIdx.x;
  {
    const int jl = t >> 2, c0 = (t & 3) * 16;
    const float4* wr = (const float4*)(Wl + (size_t)jl * 64 + c0);
    float4 w0 = wr[0], w1 = wr[1], w2 = wr[2], w3 = wr[3];
    wlT[c0 +  0][jl] = w0.x; wlT[c0 +  1][jl] = w0.y; wlT[c0 +  2][jl] = w0.z; wlT[c0 +  3][jl] = w0.w;
    wlT[c0 +  4][jl] = w1.x; wlT[c0 +  5][jl] = w1.y; wlT[c0 +  6][jl] = w1.z; wlT[c0 +  7][jl] = w1.w;
    wlT[c0 +  8][jl] = w2.x; wlT[c0 +  9][jl] = w2.y; wlT[c0 + 10][jl] = w2.z; wlT[c0 + 11][jl] = w2.w;
    wlT[c0 + 12][jl] = w3.x; wlT[c0 + 13][jl] = w3.y; wlT[c0 + 14][jl] = w3.z; wlT[c0 + 15][jl] = w3.w;
  }
  __syncthreads();  // the ONLY barrier

  const int w = t >> 6;
  const int dst = __builtin_amdgcn_readfirstlane(blockIdx.x * 4 + w);
  const int lane = t & 63;
  const int half = lane >> 5;
  const int el = lane & 31;

  const float4 qv = ((const float4*)(qs + (size_t)dst * 128))[el];
  const float4 we4 = ((const float4*)We)[el];
  const float skipv = skip[(size_t)dst * 64 + lane];
  const float xv    = x[(size_t)dst * 64 + lane];

  const float qwe = red16(qv.x * we4.x + qv.y * we4.y + qv.z * we4.z + qv.w * we4.w);

  const int base = rowptr[dst];
  const int deg  = rowptr[dst + 1] - base;
  const uint2* kv8 = (const uint2*)kvp;
  const unsigned* ep = epk + base;

  float s = 0.f, sw = 0.f;
  float sv0 = 0.f, sv1 = 0.f, sv2 = 0.f, sv3 = 0.f;

  const float SCL = 0.18033688011112042f;  // 0.125*log2(e)

#define UNPACK_W(er) __half2float(__ushort_as_half((unsigned short)((er) >> 16)))
#define PROC(u, wg, mask)                                                   \
  {                                                                         \
    const v2f k01 = __builtin_amdgcn_cvt_pk_f32_fp8((u).x, false);          \
    const v2f k23 = __builtin_amdgcn_cvt_pk_f32_fp8((u).x, true);           \
    const v2f v01 = __builtin_amdgcn_cvt_pk_f32_fp8((u).y, false);          \
    const v2f v23 = __builtin_amdgcn_cvt_pk_f32_fp8((u).y, true);           \
    const float p = red16(qv.x * k01.x + qv.y * k01.y +                     \
                          qv.z * k23.x + qv.w * k23.y);                     \
    float e_ = exp2f((p + (wg) * qwe) * SCL);                               \
    e_ = (mask) ? e_ : 0.f;                                                 \
    s += e_; sw += e_ * (wg);                                               \
    sv0 += e_ * v01.x; sv1 += e_ * v01.y;                                   \
    sv2 += e_ * v23.x; sv3 += e_ * v23.y;                                   \
  }

  int i = 0;
  for (; i + 8 <= deg; i += 8) {
    const unsigned er0 = ep[i + half];
    const unsigned er1 = ep[i + 2 + half];
    const unsigned er2 = ep[i + 4 + half];
    const unsigned er3 = ep[i + 6 + half];
    const uint2 u0 = kv8[(size_t)(er0 & 0xFFFFu) * 32 + el];
    const uint2 u1 = kv8[(size_t)(er1 & 0xFFFFu) * 32 + el];
    const uint2 u2 = kv8[(size_t)(er2 & 0xFFFFu) * 32 + el];
    const uint2 u3 = kv8[(size_t)(er3 & 0xFFFFu) * 32 + el];
    PROC(u0, UNPACK_W(er0), true)
    PROC(u1, UNPACK_W(er1), true)
    PROC(u2, UNPACK_W(er2), true)
    PROC(u3, UNPACK_W(er3), true)
  }
  for (; i + 4 <= deg; i += 4) {
    const unsigned er0 = ep[i + half];
    const unsigned er1 = ep[i + 2 + half];
    const uint2 u0 = kv8[(size_t)(er0 & 0xFFFFu) * 32 + el];
    const uint2 u1 = kv8[(size_t)(er1 & 0xFFFFu) * 32 + el];
    PROC(u0, UNPACK_W(er0), true)
    PROC(u1, UNPACK_W(er1), true)
  }
  for (; i < deg; i += 2) {
    const int idx = i + half;
    const bool valid = idx < deg;
    const unsigned er = ep[valid ? idx : (deg - 1)];
    const uint2 u = kv8[(size_t)(er & 0xFFFFu) * 32 + el];
    PROC(u, UNPACK_W(er), valid)
  }
#undef PROC
#undef UNPACK_W

  s  += __shfl_xor(s, 32);
  sw += __shfl_xor(sw, 32);
  sv0 += __shfl_xor(sv0, 32); sv1 += __shfl_xor(sv1, 32);
  sv2 += __shfl_xor(sv2, 32); sv3 += __shfl_xor(sv3, 32);

  float a0 = 0.f, a1 = 0.f, a2 = 0.f, a3 = 0.f;
  if (deg > 0) {
    const float inv = 1.f / s;
    a0 = (sv0 + sw * we4.x) * inv;
    a1 = (sv1 + sw * we4.y) * inv;
    a2 = (sv2 + sw * we4.z) * inv;
    a3 = (sv3 + sw * we4.w) * inv;
  }
  a0 = 0.5f * (a0 + __shfl_xor(a0, 16));
  a1 = 0.5f * (a1 + __shfl_xor(a1, 16));
  a2 = 0.5f * (a2 + __shfl_xor(a2, 16));
  a3 = 0.5f * (a3 + __shfl_xor(a3, 16));
  if (half == 0 && el < 16) {
    ((float4*)scx[w])[el] = make_float4(a0, a1, a2, a3);
  }
  const float hv = scx[w][lane] + skipv;

  // LN0 via dual moments
  float m1 = hv, m2 = hv * hv;
  m1 = red16(m1); m2 = red16(m2);
  m1 += __shfl_xor(m1, 16); m2 += __shfl_xor(m2, 16);
  m1 += __shfl_xor(m1, 32); m2 += __shfl_xor(m2, 32);
  const float mean = m1 * (1.f / 64.f);
  const float var = fmaxf(m2 * (1.f / 64.f) - mean * mean, 0.f);
  const float x1 = xv + (hv - mean) * rsqrtf(var + 1e-5f) * g0[lane] + b0[lane];

  // y = x1 @ Wl^T + bl via per-wave LDS broadcast
  scx[w][lane] = x1;
  float y0 = 0.f, y1 = 0.f, y2 = 0.f, y3 = 0.f;
  #pragma unroll
  for (int kk = 0; kk < 64; kk += 4) {
    const float4 xb = *(const float4*)&scx[w][kk];
    y0 += xb.x * wlT[kk][lane];
    y1 += xb.y * wlT[kk + 1][lane];
    y2 += xb.z * wlT[kk + 2][lane];
    y3 += xb.w * wlT[kk + 3][lane];
  }
  const float y = bl[lane] + (y0 + y1) + (y2 + y3);

  // LN1 via dual moments
  float n1 = y, n2 = y * y;
  n1 = red16(n1); n2 = red16(n2);
  n1 += __shfl_xor(n1, 16); n2 += __shfl_xor(n2, 16);
  n1 += __shfl_xor(n1, 32); n2 += __shfl_xor(n2, 32);
  const float mean2 = n1 * (1.f / 64.f);
  const float var2 = fmaxf(n2 * (1.f / 64.f) - mean2 * mean2, 0.f);
  out[(size_t)dst * 64 + lane] = x1 + (y - mean2) * rsqrtf(var2 + 1e-5f) * g1[lane] + b1[lane];
}

extern "C" void kernel_launch(void* const* d_in, const int* in_sizes, int n_in,
                              void* d_out, int out_size, void* d_ws, size_t ws_size,
                              hipStream_t stream) {
  const float* x     = (const float*)d_in[0];
  const int*   ei    = (const int*)d_in[1];
  const float* ea    = (const float*)d_in[2];
  const float* Wq    = (const float*)d_in[3];
  const float* bq    = (const float*)d_in[4];
  const float* Wk    = (const float*)d_in[5];
  const float* bk    = (const float*)d_in[6];
  const float* Wv    = (const float*)d_in[7];
  const float* bv    = (const float*)d_in[8];
  const float* We    = (const float*)d_in[9];
  const float* Wskip = (const float*)d_in[10];
  const float* bskip = (const float*)d_in[11];
  const float* Wl    = (const float*)d_in[12];
  const float* bl    = (const float*)d_in[13];
  const float* g0    = (const float*)d_in[14];
  const float* b0    = (const float*)d_in[15];
  const float* g1    = (const float*)d_in[16];
  const float* b1    = (const float*)d_in[17];
  float* out = (float*)d_out;

  float* ws = (float*)d_ws;
  size_t off = 0;
  float* qs   = ws + off; off += (size_t)NN * 128;
  unsigned* kvp = (unsigned*)(ws + off); off += (size_t)NN * 64;  // 256B/node fp8
  float* skip = ws + off; off += (size_t)NN * 64;
  int* cnt    = (int*)(ws + off); off += NN;
  int* rowptr = (int*)(ws + off); off += NN + 1;
  int* pos    = (int*)(ws + off); off += NE;
  unsigned* epk = (unsigned*)(ws + off); off += NE;

  (void)hipMemsetAsync(cnt, 0, (size_t)NN * sizeof(int), stream);

  dim3 gGemm((NN + 63) / 64, 3);  // y=0: q/skip, y=1: k/v, y=2: histogram+pos
  hipLaunchKernelGGL(k_gemm_qkv, gGemm, dim3(256), 0, stream,
                     x, Wq, bq, Wk, bk, Wv, bv, Wskip, bskip, ei, cnt, pos, qs, kvp, skip);
  hipLaunchKernelGGL(k_scan, dim3(49), dim3(1024), 0, stream, cnt, rowptr);
  hipLaunchKernelGGL(k_fill, dim3((NE + 255) / 256), dim3(256), 0, stream,
                     ei, ea, rowptr, pos, epk);
  hipLaunchKernelGGL(k_fused, dim3(NN / 4), dim3(256), 0, stream,
                     qs, kvp, skip, x, rowptr, epk, We,
                     Wl, bl, g0, b0, g1, b1, out);
}

// Round 17
// 141.051 us; speedup vs baseline: 1.4835x; 1.0687x over previous
//
#include <hip/hip_runtime.h>
#include <hip/hip_fp16.h>

#define NN 50000
#define NE 800000

typedef unsigned short u16;
typedef float v2f __attribute__((ext_vector_type(2)));
typedef short bf16x8 __attribute__((ext_vector_type(8)));
typedef float f32x4 __attribute__((ext_vector_type(4)));

// ---- 16-lane all-reduce on the VALU pipe via DPP (no DS ops) ----
template <int CTRL>
__device__ __forceinline__ float dpp_add(float p) {
  const int v = __builtin_amdgcn_update_dpp(0, __float_as_int(p), CTRL, 0xF, 0xF, true);
  return p + __int_as_float(v);
}
__device__ __forceinline__ float red16(float p) {
  p = dpp_add<0xB1>(p);   // quad_perm [1,0,3,2]
  p = dpp_add<0x4E>(p);   // quad_perm [2,3,0,1]
  p = dpp_add<0x141>(p);  // row_half_mirror
  p = dpp_add<0x140>(p);  // row_mirror
  return p;
}

__device__ __forceinline__ unsigned short f2bf(float f) {  // RNE fp32->bf16
  unsigned u = __float_as_uint(f);
  return (unsigned short)((u + 0x7FFFu + ((u >> 16) & 1u)) >> 16);
}
__device__ __forceinline__ unsigned pk2(float a, float b) {
  return (unsigned)f2bf(a) | ((unsigned)f2bf(b) << 16);
}

// ---------------- K1: MFMA QKV + skip GEMM (64-node tile) + histogram -------
// y==1: histogram+pos. y==0: GEMM via v_mfma_f32_16x16x32_bf16.
// q stored natural [n][128] fp32; kv [n][64] u32 fp8: entry e: k@2e, v@2e+1.
__global__ __launch_bounds__(256) void k_gemm_qkv(
    const float* __restrict__ x,
    const float* __restrict__ Wq, const float* __restrict__ bq,
    const float* __restrict__ Wk, const float* __restrict__ bk,
    const float* __restrict__ Wv, const float* __restrict__ bv,
    const float* __restrict__ Wskip, const float* __restrict__ bskip,
    const int* __restrict__ ei, int* __restrict__ cnt, int* __restrict__ pos,
    float* __restrict__ qs, unsigned* __restrict__ kvp, float* __restrict__ skip)
{
  const int t = threadIdx.x;

  if (blockIdx.y == 1) {  // histogram slice (+ per-edge bucket position)
    const int e0 = blockIdx.x * 1024 + t;
    #pragma unroll
    for (int it = 0; it < 4; it++) {
      const int e = e0 + it * 256;
      if (e < NE) pos[e] = atomicAdd(&cnt[ei[NE + e]], 1);
    }
    return;
  }

  __shared__ unsigned short xb[64][72];  // bf16 x tile, padded
  __shared__ unsigned short wb[64][72];  // bf16 W slice, padded
  __shared__ float cb[64][68];           // fp32 bounce for k/v repack
  const int tileN = blockIdx.x * 64;

  {  // stage x -> bf16 LDS (thread t writes rows of ITS OWN wave's row-tile)
    const int nl = t >> 2, c0 = (t & 3) * 16;
    const int n = tileN + nl;
    float4 a0, a1, a2, a3;
    if (n < NN) {
      const float4* xr = (const float4*)(x + (size_t)n * 64 + c0);
      a0 = xr[0]; a1 = xr[1]; a2 = xr[2]; a3 = xr[3];
    } else {
      a0 = a1 = a2 = a3 = make_float4(0.f, 0.f, 0.f, 0.f);
    }
    *(uint4*)&xb[nl][c0] =
        make_uint4(pk2(a0.x, a0.y), pk2(a0.z, a0.w), pk2(a1.x, a1.y), pk2(a1.z, a1.w));
    *(uint4*)&xb[nl][c0 + 8] =
        make_uint4(pk2(a2.x, a2.y), pk2(a2.z, a2.w), pk2(a3.x, a3.y), pk2(a3.z, a3.w));
  }

  const int w = t >> 6;          // wave -> 16-node row tile
  const int l = t & 63;
  const int rb = w * 16;
  const int frow = l & 15;
  const int fk = (l >> 4) * 8;

  // A fragments (xb rows rb..rb+15 were staged by this wave: intra-wave DS order)
  const bf16x8 a0 = *(const bf16x8*)&xb[rb + frow][fk];
  const bf16x8 a1 = *(const bf16x8*)&xb[rb + frow][fk + 32];

  for (int s = 0; s < 7; s++) {
    const float* Wb; const float* bias; int cbase; int kind;  // 0 q,1 skip,2 k,3 v
    switch (s) {
      case 0: Wb = Wq;    bias = bq;    cbase = 0;  kind = 0; break;
      case 1: Wb = Wq;    bias = bq;    cbase = 64; kind = 0; break;
      case 2: Wb = Wk;    bias = bk;    cbase = 0;  kind = 2; break;
      case 3: Wb = Wv;    bias = bv;    cbase = 0;  kind = 3; break;
      case 4: Wb = Wk;    bias = bk;    cbase = 64; kind = 2; break;
      case 5: Wb = Wv;    bias = bv;    cbase = 64; kind = 3; break;
      default: Wb = Wskip; bias = bskip; cbase = 0; kind = 1; break;
    }

    __syncthreads();  // previous slice done reading wb
    {
      const int nl = t >> 2, c0 = (t & 3) * 16;
      const float4* wr = (const float4*)(Wb + (size_t)(cbase + nl) * 64 + c0);
      float4 b0 = wr[0], b1 = wr[1], b2 = wr[2], b3 = wr[3];
      *(uint4*)&wb[nl][c0] =
          make_uint4(pk2(b0.x, b0.y), pk2(b0.z, b0.w), pk2(b1.x, b1.y), pk2(b1.z, b1.w));
      *(uint4*)&wb[nl][c0 + 8] =
          make_uint4(pk2(b2.x, b2.y), pk2(b2.z, b2.w), pk2(b3.x, b3.y), pk2(b3.z, b3.w));
    }
    __syncthreads();

    #pragma unroll
    for (int ct = 0; ct < 4; ct++) {
      const bf16x8 b0 = *(const bf16x8*)&wb[ct * 16 + frow][fk];
      const bf16x8 b1 = *(const bf16x8*)&wb[ct * 16 + frow][fk + 32];
      f32x4 acc = {0.f, 0.f, 0.f, 0.f};
      acc = __builtin_amdgcn_mfma_f32_16x16x32_bf16(a0, b0, acc, 0, 0, 0);
      acc = __builtin_amdgcn_mfma_f32_16x16x32_bf16(a1, b1, acc, 0, 0, 0);
      const int col = ct * 16 + frow;          // D: col = lane&15
      const int row0 = rb + ((l >> 4) << 2);   // D: row = (lane>>4)*4 + j
      const float bb = bias[cbase * (kind != 1 ? 1 : 0) + col];
      if (kind == 0) {
        #pragma unroll
        for (int j = 0; j < 4; j++) {
          const int n = tileN + row0 + j;
          if (n < NN) qs[(size_t)n * 128 + cbase + col] = acc[j] + bb;
        }
      } else if (kind == 1) {
        #pragma unroll
        for (int j = 0; j < 4; j++) {
          const int n = tileN + row0 + j;
          if (n < NN) skip[(size_t)n * 64 + col] = acc[j] + bb;
        }
      } else {
        #pragma unroll
        for (int j = 0; j < 4; j++) cb[row0 + j][col] = acc[j] + bb;
      }
    }

    if (kind >= 2) {  // fp8 repack from this wave's own cb rows (intra-wave)
      const int rrow = rb + (l >> 2);
      const int chb = (l & 3) * 16;
      const int n = tileN + rrow;
      if (n < NN) {
        const float4* c4 = (const float4*)&cb[rrow][chb];
        const float4 c0_ = c4[0], c1_ = c4[1], c2_ = c4[2], c3_ = c4[3];
        unsigned p0 = 0, p1 = 0, p2 = 0, p3 = 0;
        p0 = __builtin_amdgcn_cvt_pk_fp8_f32(c0_.x, c0_.y, p0, false);
        p0 = __builtin_amdgcn_cvt_pk_fp8_f32(c0_.z, c0_.w, p0, true);
        p1 = __builtin_amdgcn_cvt_pk_fp8_f32(c1_.x, c1_.y, p1, false);
        p1 = __builtin_amdgcn_cvt_pk_fp8_f32(c1_.z, c1_.w, p1, true);
        p2 = __builtin_amdgcn_cvt_pk_fp8_f32(c2_.x, c2_.y, p2, false);
        p2 = __builtin_amdgcn_cvt_pk_fp8_f32(c2_.z, c2_.w, p2, true);
        p3 = __builtin_amdgcn_cvt_pk_fp8_f32(c3_.x, c3_.y, p3, false);
        p3 = __builtin_amdgcn_cvt_pk_fp8_f32(c3_.z, c3_.w, p3, true);
        const int ebase = (cbase + chb) >> 2;
        unsigned* dstp = kvp + (size_t)n * 64 + ebase * 2 + ((kind == 3) ? 1 : 0);
        dstp[0] = p0; dstp[2] = p1; dstp[4] = p2; dstp[6] = p3;
      }
    }
  }
}

// ---------------- S2: single merged scan (49 blocks; self-computed prefix) --
__global__ __launch_bounds__(1024) void k_scan(
    const int* __restrict__ cnt, int* __restrict__ rowptr) {
  __shared__ int wsum[16];
  __shared__ int boff_s;
  const int t = threadIdx.x, lane = t & 63, wid = t >> 6;
  const int b = blockIdx.x;

  {  // prefix: sum of cnt[0 .. b*1024)
    int pre = 0;
    for (int j = t; j < b * 1024; j += 1024) pre += cnt[j];
    #pragma unroll
    for (int m = 1; m <= 32; m <<= 1) pre += __shfl_xor(pre, m);
    if (lane == 0) wsum[wid] = pre;
    __syncthreads();
    if (t == 0) {
      int s = 0;
      #pragma unroll
      for (int j = 0; j < 16; j++) s += wsum[j];
      boff_s = s;
    }
    __syncthreads();
  }

  const int i = b * 1024 + t;
  const int val = (i < NN) ? cnt[i] : 0;
  int incl = val;
  #pragma unroll
  for (int off = 1; off < 64; off <<= 1) {
    int n = __shfl_up(incl, off, 64);
    if (lane >= off) incl += n;
  }
  if (lane == 63) wsum[wid] = incl;
  __syncthreads();
  if (t < 16) {
    int wv = wsum[t];
    int wincl = wv;
    #pragma unroll
    for (int off = 1; off < 16; off <<= 1) {
      int n = __shfl_up(wincl, off, 64);
      if (t >= off) wincl += n;
    }
    wsum[t] = wincl - wv;
  }
  __syncthreads();
  if (i < NN) rowptr[i] = boff_s + wsum[wid] + incl - val;
  if (b == 0 && t == 0) rowptr[NN] = NE;
}

// ---------------- S3: pure scatter fill (no atomics), 4B records ------------
__global__ __launch_bounds__(256) void k_fill(
    const int* __restrict__ ei, const float* __restrict__ ea,
    const int* __restrict__ rowptr, const int* __restrict__ pos,
    unsigned* __restrict__ epk) {
  const int e = blockIdx.x * 256 + threadIdx.x;
  if (e < NE) {
    const int dst = ei[NE + e];
    const int idx = rowptr[dst] + pos[e];
    const unsigned rec = (unsigned)ei[e] |
        ((unsigned)__half_as_ushort(__float2half_rn(ea[e])) << 16);
    epk[idx] = rec;
  }
}

// ------- K2: per-dst softmax + agg (fp8 kv, DPP reduce, 8-edge unroll),
//         single barrier after wlT staging; waves independent afterwards -----
__global__ __launch_bounds__(256) void k_fused(
    const float* __restrict__ qs, const unsigned* __restrict__ kvp,
    const float* __restrict__ skip, const float* __restrict__ x,
    const int* __restrict__ rowptr, const unsigned* __restrict__ epk,
    const float* __restrict__ We,
    const float* __restrict__ Wl, const float* __restrict__ bl,
    const float* __restrict__ g0, const float* __restrict__ b0,
    const float* __restrict__ g1, const float* __restrict__ b1,
    float* __restrict__ out)
{
  __shared__ float wlT[64][65];   // wlT[k][j] = Wl[j][k]
  __shared__ float scx[4][64];    // per-wave scratch (transpose + x1 broadcast)
  const int t = threadIdx.x;
  {
    const int jl = t >> 2, c0 = (t & 3) * 16;
    const float4* wr = (const float4*)(Wl + (size_t)jl * 64 + c0);
    float4 w0 = wr[0], w1 = wr[1], w2 = wr[2], w3 = wr[3];
    wlT[c0 +  0][jl] = w0.x; wlT[c0 +  1][jl] = w0.y; wlT[c0 +  2][jl] = w0.z; wlT[c0 +  3][jl] = w0.w;
    wlT[c0 +  4][jl] = w1.x; wlT[c0 +  5][jl] = w1.y; wlT[c0 +  6][jl] = w1.z; wlT[c0 +  7][jl] = w1.w;
    wlT[c0 +  8][jl] = w2.x; wlT[c0 +  9][jl] = w2.y; wlT[c0 + 10][jl] = w2.z; wlT[c0 + 11][jl] = w2.w;
    wlT[c0 + 12][jl] = w3.x; wlT[c0 + 13][jl] = w3.y; wlT[c0 + 14][jl] = w3.z; wlT[c0 + 15][jl] = w3.w;
  }
  __syncthreads();  // the ONLY barrier

  const int w = t >> 6;
  const int dst = __builtin_amdgcn_readfirstlane(blockIdx.x * 4 + w);
  const int lane = t & 63;
  const int half = lane >> 5;
  const int el = lane & 31;

  const float4 qv = ((const float4*)(qs + (size_t)dst * 128))[el];
  const float4 we4 = ((const float4*)We)[el];
  const float skipv = skip[(size_t)dst * 64 + lane];
  const float xv    = x[(size_t)dst * 64 + lane];

  const float qwe = red16(qv.x * we4.x + qv.y * we4.y + qv.z * we4.z + qv.w * we4.w);

  const int base = rowptr[dst];
  const int deg  = rowptr[dst + 1] - base;
  const uint2* kv8 = (const uint2*)kvp;
  const unsigned* ep = epk + base;

  float s = 0.f, sw = 0.f;
  float sv0 = 0.f, sv1 = 0.f, sv2 = 0.f, sv3 = 0.f;

  const float SCL = 0.18033688011112042f;  // 0.125*log2(e)

#define UNPACK_W(er) __half2float(__ushort_as_half((unsigned short)((er) >> 16)))
#define PROC(u, wg, mask)                                                   \
  {                                                                         \
    const v2f k01 = __builtin_amdgcn_cvt_pk_f32_fp8((u).x, false);          \
    const v2f k23 = __builtin_amdgcn_cvt_pk_f32_fp8((u).x, true);           \
    const v2f v01 = __builtin_amdgcn_cvt_pk_f32_fp8((u).y, false);          \
    const v2f v23 = __builtin_amdgcn_cvt_pk_f32_fp8((u).y, true);           \
    const float p = red16(qv.x * k01.x + qv.y * k01.y +                     \
                          qv.z * k23.x + qv.w * k23.y);                     \
    float e_ = exp2f((p + (wg) * qwe) * SCL);                               \
    e_ = (mask) ? e_ : 0.f;                                                 \
    s += e_; sw += e_ * (wg);                                               \
    sv0 += e_ * v01.x; sv1 += e_ * v01.y;                                   \
    sv2 += e_ * v23.x; sv3 += e_ * v23.y;                                   \
  }

  int i = 0;
  for (; i + 8 <= deg; i += 8) {
    const unsigned er0 = ep[i + half];
    const unsigned er1 = ep[i + 2 + half];
    const unsigned er2 = ep[i + 4 + half];
    const unsigned er3 = ep[i + 6 + half];
    const uint2 u0 = kv8[(size_t)(er0 & 0xFFFFu) * 32 + el];
    const uint2 u1 = kv8[(size_t)(er1 & 0xFFFFu) * 32 + el];
    const uint2 u2 = kv8[(size_t)(er2 & 0xFFFFu) * 32 + el];
    const uint2 u3 = kv8[(size_t)(er3 & 0xFFFFu) * 32 + el];
    PROC(u0, UNPACK_W(er0), true)
    PROC(u1, UNPACK_W(er1), true)
    PROC(u2, UNPACK_W(er2), true)
    PROC(u3, UNPACK_W(er3), true)
  }
  for (; i + 4 <= deg; i += 4) {
    const unsigned er0 = ep[i + half];
    const unsigned er1 = ep[i + 2 + half];
    const uint2 u0 = kv8[(size_t)(er0 & 0xFFFFu) * 32 + el];
    const uint2 u1 = kv8[(size_t)(er1 & 0xFFFFu) * 32 + el];
    PROC(u0, UNPACK_W(er0), true)
    PROC(u1, UNPACK_W(er1), true)
  }
  for (; i < deg; i += 2) {
    const int idx = i + half;
    const bool valid = idx < deg;
    const unsigned er = ep[valid ? idx : (deg - 1)];
    const uint2 u = kv8[(size_t)(er & 0xFFFFu) * 32 + el];
    PROC(u, UNPACK_W(er), valid)
  }
#undef PROC
#undef UNPACK_W

  s  += __shfl_xor(s, 32);
  sw += __shfl_xor(sw, 32);
  sv0 += __shfl_xor(sv0, 32); sv1 += __shfl_xor(sv1, 32);
  sv2 += __shfl_xor(sv2, 32); sv3 += __shfl_xor(sv3, 32);

  float a0 = 0.f, a1 = 0.f, a2 = 0.f, a3 = 0.f;
  if (deg > 0) {
    const float inv = 1.f / s;
    a0 = (sv0 + sw * we4.x) * inv;
    a1 = (sv1 + sw * we4.y) * inv;
    a2 = (sv2 + sw * we4.z) * inv;
    a3 = (sv3 + sw * we4.w) * inv;
  }
  a0 = 0.5f * (a0 + __shfl_xor(a0, 16));
  a1 = 0.5f * (a1 + __shfl_xor(a1, 16));
  a2 = 0.5f * (a2 + __shfl_xor(a2, 16));
  a3 = 0.5f * (a3 + __shfl_xor(a3, 16));
  if (half == 0 && el < 16) {
    ((float4*)scx[w])[el] = make_float4(a0, a1, a2, a3);
  }
  const float hv = scx[w][lane] + skipv;

  // LN0 via dual moments
  float m1 = hv, m2 = hv * hv;
  m1 = red16(m1); m2 = red16(m2);
  m1 += __shfl_xor(m1, 16); m2 += __shfl_xor(m2, 16);
  m1 += __shfl_xor(m1, 32); m2 += __shfl_xor(m2, 32);
  const float mean = m1 * (1.f / 64.f);
  const float var = fmaxf(m2 * (1.f / 64.f) - mean * mean, 0.f);
  const float x1 = xv + (hv - mean) * rsqrtf(var + 1e-5f) * g0[lane] + b0[lane];

  // y = x1 @ Wl^T + bl via per-wave LDS broadcast
  scx[w][lane] = x1;
  float y0 = 0.f, y1 = 0.f, y2 = 0.f, y3 = 0.f;
  #pragma unroll
  for (int kk = 0; kk < 64; kk += 4) {
    const float4 xb4 = *(const float4*)&scx[w][kk];
    y0 += xb4.x * wlT[kk][lane];
    y1 += xb4.y * wlT[kk + 1][lane];
    y2 += xb4.z * wlT[kk + 2][lane];
    y3 += xb4.w * wlT[kk + 3][lane];
  }
  const float y = bl[lane] + (y0 + y1) + (y2 + y3);

  // LN1 via dual moments
  float n1 = y, n2 = y * y;
  n1 = red16(n1); n2 = red16(n2);
  n1 += __shfl_xor(n1, 16); n2 += __shfl_xor(n2, 16);
  n1 += __shfl_xor(n1, 32); n2 += __shfl_xor(n2, 32);
  const float mean2 = n1 * (1.f / 64.f);
  const float var2 = fmaxf(n2 * (1.f / 64.f) - mean2 * mean2, 0.f);
  out[(size_t)dst * 64 + lane] = x1 + (y - mean2) * rsqrtf(var2 + 1e-5f) * g1[lane] + b1[lane];
}

extern "C" void kernel_launch(void* const* d_in, const int* in_sizes, int n_in,
                              void* d_out, int out_size, void* d_ws, size_t ws_size,
                              hipStream_t stream) {
  const float* x     = (const float*)d_in[0];
  const int*   ei    = (const int*)d_in[1];
  const float* ea    = (const float*)d_in[2];
  const float* Wq    = (const float*)d_in[3];
  const float* bq    = (const float*)d_in[4];
  const float* Wk    = (const float*)d_in[5];
  const float* bk    = (const float*)d_in[6];
  const float* Wv    = (const float*)d_in[7];
  const float* bv    = (const float*)d_in[8];
  const float* We    = (const float*)d_in[9];
  const float* Wskip = (const float*)d_in[10];
  const float* bskip = (const float*)d_in[11];
  const float* Wl    = (const float*)d_in[12];
  const float* bl    = (const float*)d_in[13];
  const float* g0    = (const float*)d_in[14];
  const float* b0    = (const float*)d_in[15];
  const float* g1    = (const float*)d_in[16];
  const float* b1    = (const float*)d_in[17];
  float* out = (float*)d_out;

  float* ws = (float*)d_ws;
  size_t off = 0;
  float* qs   = ws + off; off += (size_t)NN * 128;
  unsigned* kvp = (unsigned*)(ws + off); off += (size_t)NN * 64;  // 256B/node fp8
  float* skip = ws + off; off += (size_t)NN * 64;
  int* cnt    = (int*)(ws + off); off += NN;
  int* rowptr = (int*)(ws + off); off += NN + 1;
  int* pos    = (int*)(ws + off); off += NE;
  unsigned* epk = (unsigned*)(ws + off); off += NE;

  (void)hipMemsetAsync(cnt, 0, (size_t)NN * sizeof(int), stream);

  dim3 gGemm((NN + 63) / 64, 2);  // y==1 -> histogram+pos slice
  hipLaunchKernelGGL(k_gemm_qkv, gGemm, dim3(256), 0, stream,
                     x, Wq, bq, Wk, bk, Wv, bv, Wskip, bskip, ei, cnt, pos, qs, kvp, skip);
  hipLaunchKernelGGL(k_scan, dim3(49), dim3(1024), 0, stream, cnt, rowptr);
  hipLaunchKernelGGL(k_fill, dim3((NE + 255) / 256), dim3(256), 0, stream,
                     ei, ea, rowptr, pos, epk);
  hipLaunchKernelGGL(k_fused, dim3(NN / 4), dim3(256), 0, stream,
                     qs, kvp, skip, x, rowptr, epk, We,
                     Wl, bl, g0, b0, g1, b1, out);
}